// Round 1
// baseline (1555.309 us; speedup 1.0000x reference)
//
#include <hip/hip_runtime.h>
#include <hip/hip_bf16.h>
#include <math.h>

#define SEQ   2048
#define DM    1024
#define NH    16
#define DHD   64
#define FFD   4096
#define NV    32000

typedef __bf16 bf16x8 __attribute__((ext_vector_type(8)));
typedef float  f32x4  __attribute__((ext_vector_type(4)));

static __device__ __forceinline__ unsigned short f2bf(float f) {
  unsigned int x = __float_as_uint(f);
  return (unsigned short)((x + 0x7fffu + ((x >> 16) & 1u)) >> 16);
}

static __device__ __forceinline__ bf16x8 ld_frag(const unsigned short* p) {
  union { uint4 u; bf16x8 v; } r;
  r.u = *(const uint4*)p;
  return r.v;
}

// ---- transpose + f32->bf16 convert: out[n][k] = bf16(in[k][n]) ----
__global__ __launch_bounds__(256)
void k_transpose_bf16(const float* __restrict__ in, unsigned short* __restrict__ out,
                      int K, int N) {
  __shared__ float tile[32][33];
  const int bk = blockIdx.x * 32, bn = blockIdx.y * 32;
  const int tx = threadIdx.x & 31, ty = threadIdx.x >> 5;
#pragma unroll
  for (int r = ty; r < 32; r += 8)
    tile[r][tx] = in[(size_t)(bk + r) * N + (bn + tx)];
  __syncthreads();
#pragma unroll
  for (int r = ty; r < 32; r += 8)
    out[(size_t)(bn + r) * K + (bk + tx)] = f2bf(tile[tx][r]);
}

// ---- embedding: h[i][d] = tok[x[i]][d] + pos[i][d] ----
__global__ __launch_bounds__(256)
void k_embed(const int* __restrict__ x, const float* __restrict__ tok,
             const float* __restrict__ pos, float* __restrict__ h) {
  const int row = blockIdx.x;
  const int d = threadIdx.x * 4;
  const int tk = x[row];
  float4 a = *(const float4*)(tok + (size_t)tk * DM + d);
  float4 p = *(const float4*)(pos + (size_t)row * DM + d);
  float4 o; o.x = a.x + p.x; o.y = a.y + p.y; o.z = a.z + p.z; o.w = a.w + p.w;
  *(float4*)(h + (size_t)row * DM + d) = o;
}

// ---- LayerNorm(in) -> bf16 out ----
__global__ __launch_bounds__(256)
void k_ln_bf16(const float* __restrict__ in, const float* __restrict__ g,
               const float* __restrict__ b, unsigned short* __restrict__ out) {
  const int row = blockIdx.x, t = threadIdx.x;
  float4 v = *(const float4*)(in + (size_t)row * DM + t * 4);
  float s = v.x + v.y + v.z + v.w;
  float q = v.x * v.x + v.y * v.y + v.z * v.z + v.w * v.w;
#pragma unroll
  for (int o = 32; o; o >>= 1) { s += __shfl_xor(s, o); q += __shfl_xor(q, o); }
  __shared__ float ls[4], lq[4];
  if ((t & 63) == 0) { ls[t >> 6] = s; lq[t >> 6] = q; }
  __syncthreads();
  s = ls[0] + ls[1] + ls[2] + ls[3];
  q = lq[0] + lq[1] + lq[2] + lq[3];
  const float mean = s * (1.f / DM);
  const float rstd = rsqrtf(q * (1.f / DM) - mean * mean + 1e-5f);
  float4 gg = *(const float4*)(g + t * 4);
  float4 bb = *(const float4*)(b + t * 4);
  ushort4 o4;
  o4.x = f2bf((v.x - mean) * rstd * gg.x + bb.x);
  o4.y = f2bf((v.y - mean) * rstd * gg.y + bb.y);
  o4.z = f2bf((v.z - mean) * rstd * gg.z + bb.z);
  o4.w = f2bf((v.w - mean) * rstd * gg.w + bb.w);
  *(ushort4*)(out + (size_t)row * DM + t * 4) = o4;
}

// ---- h += LayerNorm(in) ----
__global__ __launch_bounds__(256)
void k_add_ln(float* __restrict__ h, const float* __restrict__ in,
              const float* __restrict__ g, const float* __restrict__ b) {
  const int row = blockIdx.x, t = threadIdx.x;
  float4 v = *(const float4*)(in + (size_t)row * DM + t * 4);
  float s = v.x + v.y + v.z + v.w;
  float q = v.x * v.x + v.y * v.y + v.z * v.z + v.w * v.w;
#pragma unroll
  for (int o = 32; o; o >>= 1) { s += __shfl_xor(s, o); q += __shfl_xor(q, o); }
  __shared__ float ls[4], lq[4];
  if ((t & 63) == 0) { ls[t >> 6] = s; lq[t >> 6] = q; }
  __syncthreads();
  s = ls[0] + ls[1] + ls[2] + ls[3];
  q = lq[0] + lq[1] + lq[2] + lq[3];
  const float mean = s * (1.f / DM);
  const float rstd = rsqrtf(q * (1.f / DM) - mean * mean + 1e-5f);
  float4 gg = *(const float4*)(g + t * 4);
  float4 bb = *(const float4*)(b + t * 4);
  float4 hv = *(const float4*)(h + (size_t)row * DM + t * 4);
  hv.x += (v.x - mean) * rstd * gg.x + bb.x;
  hv.y += (v.y - mean) * rstd * gg.y + bb.y;
  hv.z += (v.z - mean) * rstd * gg.z + bb.z;
  hv.w += (v.w - mean) * rstd * gg.w + bb.w;
  *(float4*)(h + (size_t)row * DM + t * 4) = hv;
}

// ---- GEMM: C[M][N] = A[M][K](bf16) @ Bt[N][K](bf16)^T, fp32 accum ----
// EPI: 0 = store bf16 (no bias); 1 = +bias, store f32; 2 = +bias, gelu, store bf16;
//      3 = +bias, +res, store f32
template<int EPI>
__global__ __launch_bounds__(256)
void k_gemm_bt(const unsigned short* __restrict__ A, const unsigned short* __restrict__ Bt,
               float* outF, unsigned short* outB,
               const float* __restrict__ bias, const float* res,
               int M, int N, int K) {
  __shared__ __align__(16) unsigned short As[128 * 40];
  __shared__ __align__(16) unsigned short Bs[128 * 40];
  const int bn = blockIdx.x, bm = blockIdx.y;
  const int t = threadIdx.x;
  const int lane = t & 63, w = t >> 6;
  const int wm = w >> 1, wn = w & 1;
  const int lr = lane & 15, lg = lane >> 4;

  const int srow = t >> 1;           // 0..127
  const int scol = (t & 1) << 4;     // 0 or 16
  const unsigned short* gA = A + (size_t)(bm * 128 + srow) * K + scol;
  const unsigned short* gB = Bt + (size_t)(bn * 128 + srow) * K + scol;
  unsigned short* wA = &As[srow * 40 + scol];
  unsigned short* wB = &Bs[srow * 40 + scol];

  const f32x4 zero = {0.f, 0.f, 0.f, 0.f};
  f32x4 acc[4][4];
#pragma unroll
  for (int i = 0; i < 4; ++i)
#pragma unroll
    for (int j = 0; j < 4; ++j) acc[i][j] = zero;

  for (int k0 = 0; k0 < K; k0 += 32) {
    uint4 a0 = *(const uint4*)(gA + k0);
    uint4 a1 = *(const uint4*)(gA + k0 + 8);
    uint4 b0 = *(const uint4*)(gB + k0);
    uint4 b1 = *(const uint4*)(gB + k0 + 8);
    if (k0) __syncthreads();
    *(uint4*)wA = a0;
    *(uint4*)(wA + 8) = a1;
    *(uint4*)wB = b0;
    *(uint4*)(wB + 8) = b1;
    __syncthreads();

    bf16x8 af[4], bfr[4];
#pragma unroll
    for (int mt = 0; mt < 4; ++mt)
      af[mt] = ld_frag(&As[(wm * 64 + mt * 16 + lr) * 40 + lg * 8]);
#pragma unroll
    for (int nt = 0; nt < 4; ++nt)
      bfr[nt] = ld_frag(&Bs[(wn * 64 + nt * 16 + lr) * 40 + lg * 8]);
#pragma unroll
    for (int mt = 0; mt < 4; ++mt)
#pragma unroll
      for (int nt = 0; nt < 4; ++nt)
        acc[mt][nt] = __builtin_amdgcn_mfma_f32_16x16x32_bf16(af[mt], bfr[nt], acc[mt][nt], 0, 0, 0);
  }

  const int rbase = bm * 128 + wm * 64;
  const int cbase = bn * 128 + wn * 64;
#pragma unroll
  for (int mt = 0; mt < 4; ++mt) {
#pragma unroll
    for (int nt = 0; nt < 4; ++nt) {
      const int col = cbase + nt * 16 + lr;
      float bv = 0.f;
      if constexpr (EPI != 0) bv = bias[col];
#pragma unroll
      for (int r = 0; r < 4; ++r) {
        const int row = rbase + mt * 16 + lg * 4 + r;
        float v = acc[mt][nt][r] + bv;
        if constexpr (EPI == 2) v = 0.5f * v * (1.f + erff(v * 0.70710678118f));
        if constexpr (EPI == 3) v += res[(size_t)row * N + col];
        if constexpr (EPI == 0 || EPI == 2) outB[(size_t)row * N + col] = f2bf(v);
        else                                outF[(size_t)row * N + col] = v;
      }
    }
  }
}

// ---- fused causal ReLA attention: o = (relu(mask(Q K^T)) * scale) @ V ----
// qkv: bf16 [SEQ][3*DM], layout [q | k | v]; obf: bf16 [SEQ][DM] (head-major cols)
__global__ __launch_bounds__(256)
void k_rela_attn(const unsigned short* __restrict__ qkv, unsigned short* __restrict__ obf) {
  const int qb = blockIdx.x;   // 0..31 (64 q rows each)
  const int hd = blockIdx.y;   // 0..15
  const int t = threadIdx.x;
  const int lane = t & 63, w = t >> 6;
  const int lr = lane & 15, lg = lane >> 4;

  __shared__ __align__(16) unsigned short Qs[64 * 72];
  __shared__ __align__(16) unsigned short Ks[64 * 72];
  __shared__ __align__(16) unsigned short Vs[64 * 72];  // transposed: [dh][kv]
  __shared__ __align__(16) unsigned short Ps[4][16 * 72];

  const int srow = t >> 2;            // 0..63
  const int scol = (t & 3) << 4;      // 0,16,32,48

  {
    const unsigned short* g = qkv + (size_t)(qb * 64 + srow) * (3 * DM) + hd * DHD + scol;
    *(uint4*)&Qs[srow * 72 + scol] = *(const uint4*)g;
    *(uint4*)&Qs[srow * 72 + scol + 8] = *(const uint4*)(g + 8);
  }
  __syncthreads();

  bf16x8 qf[2];
#pragma unroll
  for (int ks = 0; ks < 2; ++ks)
    qf[ks] = ld_frag(&Qs[(w * 16 + lr) * 72 + ks * 32 + lg * 8]);

  const f32x4 zero = {0.f, 0.f, 0.f, 0.f};
  f32x4 acco[4];
#pragma unroll
  for (int nt = 0; nt < 4; ++nt) acco[nt] = zero;

  for (int kt = 0; kt <= qb; ++kt) {
    __syncthreads();
    {
      const unsigned short* gk = qkv + (size_t)(kt * 64 + srow) * (3 * DM) + DM + hd * DHD + scol;
      *(uint4*)&Ks[srow * 72 + scol] = *(const uint4*)gk;
      *(uint4*)&Ks[srow * 72 + scol + 8] = *(const uint4*)(gk + 8);
      const unsigned short* gv = qkv + (size_t)(kt * 64 + srow) * (3 * DM) + 2 * DM + hd * DHD + scol;
      union { uint4 u[2]; unsigned short e[16]; } vv;
      vv.u[0] = *(const uint4*)gv;
      vv.u[1] = *(const uint4*)(gv + 8);
#pragma unroll
      for (int j = 0; j < 16; ++j)
        Vs[(scol + j) * 72 + srow] = vv.e[j];
    }
    __syncthreads();

    f32x4 sv[4];
#pragma unroll
    for (int nt = 0; nt < 4; ++nt) sv[nt] = zero;
#pragma unroll
    for (int ks = 0; ks < 2; ++ks) {
#pragma unroll
      for (int nt = 0; nt < 4; ++nt) {
        bf16x8 kf = ld_frag(&Ks[(nt * 16 + lr) * 72 + ks * 32 + lg * 8]);
        sv[nt] = __builtin_amdgcn_mfma_f32_16x16x32_bf16(qf[ks], kf, sv[nt], 0, 0, 0);
      }
    }

    const bool diag = (kt == qb);
#pragma unroll
    for (int nt = 0; nt < 4; ++nt) {
#pragma unroll
      for (int r = 0; r < 4; ++r) {
        float v = fmaxf(sv[nt][r], 0.f) * 0.125f;
        if (diag) {
          const int i = w * 16 + lg * 4 + r;
          const int j = nt * 16 + lr;
          if (j > i) v = 0.f;
        }
        Ps[w][(lg * 4 + r) * 72 + nt * 16 + lr] = f2bf(v);
      }
    }

#pragma unroll
    for (int ks = 0; ks < 2; ++ks) {
      bf16x8 pf = ld_frag(&Ps[w][lr * 72 + ks * 32 + lg * 8]);
#pragma unroll
      for (int nt = 0; nt < 4; ++nt) {
        bf16x8 vf = ld_frag(&Vs[(nt * 16 + lr) * 72 + ks * 32 + lg * 8]);
        acco[nt] = __builtin_amdgcn_mfma_f32_16x16x32_bf16(pf, vf, acco[nt], 0, 0, 0);
      }
    }
  }

#pragma unroll
  for (int nt = 0; nt < 4; ++nt) {
#pragma unroll
    for (int r = 0; r < 4; ++r) {
      const int row = qb * 64 + w * 16 + lg * 4 + r;
      const int col = hd * DHD + nt * 16 + lr;
      obf[(size_t)row * DM + col] = f2bf(acco[nt][r]);
    }
  }
}

extern "C" void kernel_launch(void* const* d_in, const int* in_sizes, int n_in,
                              void* d_out, int out_size, void* d_ws, size_t ws_size,
                              hipStream_t stream) {
  const int*   x       = (const int*)d_in[0];
  const float* tok_emb = (const float*)d_in[1];
  const float* pos_emb = (const float*)d_in[2];
  const float* attn_ng = (const float*)d_in[3];
  const float* attn_nb = (const float*)d_in[4];
  const float* wqkv    = (const float*)d_in[5];
  const float* wo      = (const float*)d_in[6];
  const float* bo      = (const float*)d_in[7];
  const float* out_ng  = (const float*)d_in[8];
  const float* out_nb  = (const float*)d_in[9];
  const float* ff_ng   = (const float*)d_in[10];
  const float* ff_nb   = (const float*)d_in[11];
  const float* w1      = (const float*)d_in[12];
  const float* b1      = (const float*)d_in[13];
  const float* w2      = (const float*)d_in[14];
  const float* b2      = (const float*)d_in[15];
  const float* fin_g   = (const float*)d_in[16];
  const float* fin_b   = (const float*)d_in[17];
  const float* w_logit = (const float*)d_in[18];
  const float* b_logit = (const float*)d_in[19];
  float* out = (float*)d_out;

  char* ws = (char*)d_ws;
  size_t off = 0;
  auto alloc = [&](size_t bytes) -> void* {
    void* p = ws + off;
    off = (off + bytes + 255) & ~(size_t)255;
    return p;
  };
  unsigned short* wqkvT = (unsigned short*)alloc(4ull * 3072 * 1024 * 2);
  unsigned short* woT   = (unsigned short*)alloc(4ull * 1024 * 1024 * 2);
  unsigned short* w1T   = (unsigned short*)alloc(4ull * 4096 * 1024 * 2);
  unsigned short* w2T   = (unsigned short*)alloc(4ull * 1024 * 4096 * 2);
  unsigned short* wlogT = (unsigned short*)alloc((size_t)NV * 1024 * 2);
  float*          h     = (float*)alloc((size_t)SEQ * DM * 4);
  unsigned short* ybf   = (unsigned short*)alloc((size_t)SEQ * DM * 2);
  unsigned short* qkvbf = (unsigned short*)alloc((size_t)SEQ * 3 * DM * 2);
  unsigned short* obf   = (unsigned short*)alloc((size_t)SEQ * DM * 2);
  float*          tmpf  = (float*)alloc((size_t)SEQ * DM * 4);
  unsigned short* ffbf  = (unsigned short*)alloc((size_t)SEQ * FFD * 2);
  (void)ws_size; (void)in_sizes; (void)n_in; (void)out_size;

  const dim3 B(256);

  // weight convert+transpose (per call; deterministic)
  for (int l = 0; l < 4; ++l) {
    k_transpose_bf16<<<dim3(1024 / 32, 3072 / 32), B, 0, stream>>>(
        wqkv + (size_t)l * 1024 * 3072, wqkvT + (size_t)l * 3072 * 1024, 1024, 3072);
    k_transpose_bf16<<<dim3(1024 / 32, 1024 / 32), B, 0, stream>>>(
        wo + (size_t)l * 1024 * 1024, woT + (size_t)l * 1024 * 1024, 1024, 1024);
    k_transpose_bf16<<<dim3(1024 / 32, 4096 / 32), B, 0, stream>>>(
        w1 + (size_t)l * 1024 * 4096, w1T + (size_t)l * 4096 * 1024, 1024, 4096);
    k_transpose_bf16<<<dim3(4096 / 32, 1024 / 32), B, 0, stream>>>(
        w2 + (size_t)l * 4096 * 1024, w2T + (size_t)l * 1024 * 4096, 4096, 1024);
  }
  k_transpose_bf16<<<dim3(1024 / 32, NV / 32), B, 0, stream>>>(w_logit, wlogT, 1024, NV);

  k_embed<<<SEQ, B, 0, stream>>>(x, tok_emb, pos_emb, h);

  for (int l = 0; l < 4; ++l) {
    k_ln_bf16<<<SEQ, B, 0, stream>>>(h, attn_ng + l * DM, attn_nb + l * DM, ybf);
    k_gemm_bt<0><<<dim3(3072 / 128, SEQ / 128), B, 0, stream>>>(
        ybf, wqkvT + (size_t)l * 3072 * 1024, nullptr, qkvbf, nullptr, nullptr, SEQ, 3072, 1024);
    k_rela_attn<<<dim3(SEQ / 64, NH), B, 0, stream>>>(qkvbf, obf);
    k_gemm_bt<1><<<dim3(1024 / 128, SEQ / 128), B, 0, stream>>>(
        obf, woT + (size_t)l * 1024 * 1024, tmpf, nullptr, bo + l * DM, nullptr, SEQ, 1024, 1024);
    k_add_ln<<<SEQ, B, 0, stream>>>(h, tmpf, out_ng + l * DM, out_nb + l * DM);
    k_ln_bf16<<<SEQ, B, 0, stream>>>(h, ff_ng + l * DM, ff_nb + l * DM, ybf);
    k_gemm_bt<2><<<dim3(4096 / 128, SEQ / 128), B, 0, stream>>>(
        ybf, w1T + (size_t)l * 4096 * 1024, nullptr, ffbf, b1 + l * FFD, nullptr, SEQ, 4096, 1024);
    k_gemm_bt<3><<<dim3(1024 / 128, SEQ / 128), B, 0, stream>>>(
        ffbf, w2T + (size_t)l * 1024 * 4096, h, nullptr, b2 + l * DM, h, SEQ, 1024, 4096);
  }

  k_ln_bf16<<<SEQ, B, 0, stream>>>(h, fin_g, fin_b, ybf);
  k_gemm_bt<1><<<dim3(NV / 128, SEQ / 128), B, 0, stream>>>(
      ybf, wlogT, out, nullptr, b_logit, nullptr, SEQ, NV, 1024);
}

// Round 2
// 1468.486 us; speedup vs baseline: 1.0591x; 1.0591x over previous
//
#include <hip/hip_runtime.h>
#include <hip/hip_bf16.h>
#include <math.h>

#define SEQ   2048
#define DM    1024
#define NH    16
#define DHD   64
#define FFD   4096
#define NV    32000

typedef __bf16 bf16x8 __attribute__((ext_vector_type(8)));
typedef float  f32x4  __attribute__((ext_vector_type(4)));

typedef __attribute__((address_space(1))) void* gas_ptr;
typedef __attribute__((address_space(3))) void* las_ptr;

static __device__ __forceinline__ void gload16(const void* g, void* l) {
  __builtin_amdgcn_global_load_lds((gas_ptr)g, (las_ptr)l, 16, 0, 0);
}

static __device__ __forceinline__ unsigned short f2bf(float f) {
  unsigned int x = __float_as_uint(f);
  return (unsigned short)((x + 0x7fffu + ((x >> 16) & 1u)) >> 16);
}

static __device__ __forceinline__ bf16x8 ld_frag(const unsigned short* p) {
  union { uint4 u; bf16x8 v; } r;
  r.u = *(const uint4*)p;
  return r.v;
}

// ---- transpose + f32->bf16 convert: out[n][k] = bf16(in[k][n]) ----
__global__ __launch_bounds__(256)
void k_transpose_bf16(const float* __restrict__ in, unsigned short* __restrict__ out,
                      int K, int N) {
  __shared__ float tile[32][33];
  const int bk = blockIdx.x * 32, bn = blockIdx.y * 32;
  const int tx = threadIdx.x & 31, ty = threadIdx.x >> 5;
#pragma unroll
  for (int r = ty; r < 32; r += 8)
    tile[r][tx] = in[(size_t)(bk + r) * N + (bn + tx)];
  __syncthreads();
#pragma unroll
  for (int r = ty; r < 32; r += 8)
    out[(size_t)(bn + r) * K + (bk + tx)] = f2bf(tile[tx][r]);
}

// ---- per-head V transpose: vT[h*64+d][s] = qkv[s][2*DM + h*64 + d] ----
__global__ __launch_bounds__(256)
void k_vT(const unsigned short* __restrict__ qkv, unsigned short* __restrict__ vT) {
  __shared__ unsigned short tile[32][33];
  const int bs = blockIdx.x * 32, bd = blockIdx.y * 32;
  const int tx = threadIdx.x & 31, ty = threadIdx.x >> 5;
#pragma unroll
  for (int r = ty; r < 32; r += 8)
    tile[r][tx] = qkv[(size_t)(bs + r) * (3 * DM) + 2 * DM + bd + tx];
  __syncthreads();
#pragma unroll
  for (int r = ty; r < 32; r += 8)
    vT[(size_t)(bd + r) * SEQ + bs + tx] = tile[tx][r];
}

// ---- embedding ----
__global__ __launch_bounds__(256)
void k_embed(const int* __restrict__ x, const float* __restrict__ tok,
             const float* __restrict__ pos, float* __restrict__ h) {
  const int row = blockIdx.x;
  const int d = threadIdx.x * 4;
  const int tk = x[row];
  float4 a = *(const float4*)(tok + (size_t)tk * DM + d);
  float4 p = *(const float4*)(pos + (size_t)row * DM + d);
  float4 o; o.x = a.x + p.x; o.y = a.y + p.y; o.z = a.z + p.z; o.w = a.w + p.w;
  *(float4*)(h + (size_t)row * DM + d) = o;
}

// ---- LayerNorm(in) -> bf16 out ----
__global__ __launch_bounds__(256)
void k_ln_bf16(const float* __restrict__ in, const float* __restrict__ g,
               const float* __restrict__ b, unsigned short* __restrict__ out) {
  const int row = blockIdx.x, t = threadIdx.x;
  float4 v = *(const float4*)(in + (size_t)row * DM + t * 4);
  float s = v.x + v.y + v.z + v.w;
  float q = v.x * v.x + v.y * v.y + v.z * v.z + v.w * v.w;
#pragma unroll
  for (int o = 32; o; o >>= 1) { s += __shfl_xor(s, o); q += __shfl_xor(q, o); }
  __shared__ float ls[4], lq[4];
  if ((t & 63) == 0) { ls[t >> 6] = s; lq[t >> 6] = q; }
  __syncthreads();
  s = ls[0] + ls[1] + ls[2] + ls[3];
  q = lq[0] + lq[1] + lq[2] + lq[3];
  const float mean = s * (1.f / DM);
  const float rstd = rsqrtf(q * (1.f / DM) - mean * mean + 1e-5f);
  float4 gg = *(const float4*)(g + t * 4);
  float4 bb = *(const float4*)(b + t * 4);
  ushort4 o4;
  o4.x = f2bf((v.x - mean) * rstd * gg.x + bb.x);
  o4.y = f2bf((v.y - mean) * rstd * gg.y + bb.y);
  o4.z = f2bf((v.z - mean) * rstd * gg.z + bb.z);
  o4.w = f2bf((v.w - mean) * rstd * gg.w + bb.w);
  *(ushort4*)(out + (size_t)row * DM + t * 4) = o4;
}

// ---- h += LayerNorm(in) ----
__global__ __launch_bounds__(256)
void k_add_ln(float* __restrict__ h, const float* __restrict__ in,
              const float* __restrict__ g, const float* __restrict__ b) {
  const int row = blockIdx.x, t = threadIdx.x;
  float4 v = *(const float4*)(in + (size_t)row * DM + t * 4);
  float s = v.x + v.y + v.z + v.w;
  float q = v.x * v.x + v.y * v.y + v.z * v.z + v.w * v.w;
#pragma unroll
  for (int o = 32; o; o >>= 1) { s += __shfl_xor(s, o); q += __shfl_xor(q, o); }
  __shared__ float ls[4], lq[4];
  if ((t & 63) == 0) { ls[t >> 6] = s; lq[t >> 6] = q; }
  __syncthreads();
  s = ls[0] + ls[1] + ls[2] + ls[3];
  q = lq[0] + lq[1] + lq[2] + lq[3];
  const float mean = s * (1.f / DM);
  const float rstd = rsqrtf(q * (1.f / DM) - mean * mean + 1e-5f);
  float4 gg = *(const float4*)(g + t * 4);
  float4 bb = *(const float4*)(b + t * 4);
  float4 hv = *(const float4*)(h + (size_t)row * DM + t * 4);
  hv.x += (v.x - mean) * rstd * gg.x + bb.x;
  hv.y += (v.y - mean) * rstd * gg.y + bb.y;
  hv.z += (v.z - mean) * rstd * gg.z + bb.z;
  hv.w += (v.w - mean) * rstd * gg.w + bb.w;
  *(float4*)(h + (size_t)row * DM + t * 4) = hv;
}

// ---- GEMM: C[M][N] = A[M][K](bf16) @ Bt[N][K](bf16)^T, fp32 accum ----
// m97 structure: global_load_lds width=16, linear LDS [128][32] with
// source-pre-swizzle (chunk ^= (row>>1)&3) + swizzled ds_read (2-way conflicts).
// Block swizzle: bijective XCD chunking + column-major tile walk (A L2-resident).
template<int EPI>
__global__ __launch_bounds__(256)
void k_gemm_bt(const unsigned short* __restrict__ A, const unsigned short* __restrict__ Bt,
               float* __restrict__ outF, unsigned short* __restrict__ outB,
               const float* __restrict__ bias, const float* __restrict__ res,
               int N, int K, int gm) {
  __shared__ __align__(16) unsigned short As[128 * 32];
  __shared__ __align__(16) unsigned short Bs[128 * 32];
  const int nwg = gridDim.x, pid = blockIdx.x;
  const int qq = nwg >> 3, rr = nwg & 7;
  const int xcd = pid & 7, lo = pid >> 3;
  const int wg = ((xcd < rr) ? xcd * (qq + 1) : rr * (qq + 1) + (xcd - rr) * qq) + lo;
  const int bm = wg % gm, bn = wg / gm;
  const int t = threadIdx.x, lane = t & 63, w = t >> 6;
  const int wm = w >> 1, wn = w & 1, lr = lane & 15, lg = lane >> 4;

  // staging: instr i covers rows [i*16, i*16+16) of the [128][32] tile
  const int i0 = w * 2, i1 = i0 + 1;
  const int srow = lane >> 2;                               // 0..15
  const int scol = ((lane & 3) ^ ((lane >> 3) & 3)) << 3;   // swizzled 8-ushort chunk
  const unsigned short* gA0 = A  + (size_t)(bm * 128 + i0 * 16 + srow) * K + scol;
  const unsigned short* gA1 = A  + (size_t)(bm * 128 + i1 * 16 + srow) * K + scol;
  const unsigned short* gB0 = Bt + (size_t)(bn * 128 + i0 * 16 + srow) * K + scol;
  const unsigned short* gB1 = Bt + (size_t)(bn * 128 + i1 * 16 + srow) * K + scol;
  unsigned short* lA0 = As + i0 * 512;
  unsigned short* lA1 = As + i1 * 512;
  unsigned short* lB0 = Bs + i0 * 512;
  unsigned short* lB1 = Bs + i1 * 512;

  const f32x4 zero = {0.f, 0.f, 0.f, 0.f};
  f32x4 acc[4][4];
#pragma unroll
  for (int i = 0; i < 4; ++i)
#pragma unroll
    for (int j = 0; j < 4; ++j) acc[i][j] = zero;

  for (int k0 = 0; k0 < K; k0 += 32) {
    gload16(gA0 + k0, lA0);
    gload16(gA1 + k0, lA1);
    gload16(gB0 + k0, lB0);
    gload16(gB1 + k0, lB1);
    __syncthreads();

    bf16x8 af[4], bfr[4];
#pragma unroll
    for (int mt = 0; mt < 4; ++mt) {
      const int row = wm * 64 + mt * 16 + lr;
      af[mt] = ld_frag(&As[row * 32 + ((lg ^ ((row >> 1) & 3)) << 3)]);
    }
#pragma unroll
    for (int nt = 0; nt < 4; ++nt) {
      const int row = wn * 64 + nt * 16 + lr;
      bfr[nt] = ld_frag(&Bs[row * 32 + ((lg ^ ((row >> 1) & 3)) << 3)]);
    }
#pragma unroll
    for (int mt = 0; mt < 4; ++mt)
#pragma unroll
      for (int nt = 0; nt < 4; ++nt)
        acc[mt][nt] = __builtin_amdgcn_mfma_f32_16x16x32_bf16(af[mt], bfr[nt], acc[mt][nt], 0, 0, 0);
    __syncthreads();
  }

  const int rbase = bm * 128 + wm * 64;
  const int cbase = bn * 128 + wn * 64;
#pragma unroll
  for (int mt = 0; mt < 4; ++mt) {
#pragma unroll
    for (int nt = 0; nt < 4; ++nt) {
      const int col = cbase + nt * 16 + lr;
      float bv = 0.f;
      if constexpr (EPI != 0) bv = bias[col];
#pragma unroll
      for (int r = 0; r < 4; ++r) {
        const int row = rbase + mt * 16 + lg * 4 + r;
        float v = acc[mt][nt][r] + bv;
        if constexpr (EPI == 2) v = 0.5f * v * (1.f + erff(v * 0.70710678118f));
        if constexpr (EPI == 3) v += res[(size_t)row * N + col];
        if constexpr (EPI == 0 || EPI == 2) outB[(size_t)row * N + col] = f2bf(v);
        else                                outF[(size_t)row * N + col] = v;
      }
    }
  }
}

// ---- fused causal ReLA attention, balanced q-strip pairs ----
// block (jb, hd) computes q-strips qbA=jb and qbB=31-jb in ONE kv loop:
// per-block MFMA-tile count = (jb+1) + (32-jb) = 33 (uniform).
__global__ __launch_bounds__(256)
void k_rela_attn(const unsigned short* __restrict__ qkv,
                 const unsigned short* __restrict__ vT,
                 unsigned short* __restrict__ obf) {
  const int jb = blockIdx.x;      // 0..15
  const int hd = blockIdx.y;      // 0..15
  const int qbA = jb, qbB = 31 - jb;
  const int t = threadIdx.x, lane = t & 63, w = t >> 6;
  const int lr = lane & 15, lg = lane >> 4;

  __shared__ __align__(16) unsigned short Qs[128 * 64];
  __shared__ __align__(16) unsigned short Ks[64 * 64];
  __shared__ __align__(16) unsigned short Vs[64 * 64];   // [d][kv]
  __shared__ __align__(16) unsigned short Ps[4][16 * 72];

  const int sr8 = lane >> 3;                    // row-within-instr 0..7
  const int sch = ((lane & 7) ^ sr8) << 3;      // swizzled 8-ushort chunk

  // stage Q (both strips): 16 instrs x 1024B
#pragma unroll
  for (int qi = 0; qi < 4; ++qi) {
    const int i = w * 4 + qi;
    const int rl = i * 8 + sr8;                 // 0..127
    const int grow = (rl < 64) ? (qbA * 64 + rl) : (qbB * 64 + rl - 64);
    gload16(qkv + (size_t)grow * (3 * DM) + hd * DHD + sch, Qs + i * 512);
  }
  __syncthreads();

  bf16x8 qfA[2], qfB[2];
#pragma unroll
  for (int ks = 0; ks < 2; ++ks) {
    const int rowA = w * 16 + lr;
    qfA[ks] = ld_frag(&Qs[rowA * 64 + (((ks * 4 + lg) ^ (lr & 7)) << 3)]);
    const int rowB = 64 + w * 16 + lr;
    qfB[ks] = ld_frag(&Qs[rowB * 64 + (((ks * 4 + lg) ^ (lr & 7)) << 3)]);
  }

  const f32x4 zero = {0.f, 0.f, 0.f, 0.f};
  f32x4 accA[4], accB[4];
#pragma unroll
  for (int nt = 0; nt < 4; ++nt) { accA[nt] = zero; accB[nt] = zero; }

  auto tile_step = [&](const bf16x8* qf, f32x4* acc, int qb, int kt) {
    f32x4 sv[4];
#pragma unroll
    for (int nt = 0; nt < 4; ++nt) sv[nt] = zero;
#pragma unroll
    for (int ks = 0; ks < 2; ++ks)
#pragma unroll
      for (int nt = 0; nt < 4; ++nt) {
        bf16x8 kf = ld_frag(&Ks[(nt * 16 + lr) * 64 + (((ks * 4 + lg) ^ (lr & 7)) << 3)]);
        sv[nt] = __builtin_amdgcn_mfma_f32_16x16x32_bf16(qf[ks], kf, sv[nt], 0, 0, 0);
      }
    const bool diag = (kt == qb);
#pragma unroll
    for (int nt = 0; nt < 4; ++nt)
#pragma unroll
      for (int r = 0; r < 4; ++r) {
        float v = fmaxf(sv[nt][r], 0.f) * 0.125f;
        if (diag) {
          const int ii = w * 16 + lg * 4 + r;
          const int jj = nt * 16 + lr;
          if (jj > ii) v = 0.f;
        }
        Ps[w][(lg * 4 + r) * 72 + nt * 16 + lr] = f2bf(v);
      }
#pragma unroll
    for (int ks = 0; ks < 2; ++ks) {
      bf16x8 pf = ld_frag(&Ps[w][lr * 72 + ks * 32 + lg * 8]);
#pragma unroll
      for (int nt = 0; nt < 4; ++nt) {
        bf16x8 vf = ld_frag(&Vs[(nt * 16 + lr) * 64 + (((ks * 4 + lg) ^ (lr & 7)) << 3)]);
        acc[nt] = __builtin_amdgcn_mfma_f32_16x16x32_bf16(pf, vf, acc[nt], 0, 0, 0);
      }
    }
  };

  for (int kt = 0; kt <= qbB; ++kt) {
    __syncthreads();
#pragma unroll
    for (int qi = 0; qi < 2; ++qi) {
      const int i = w * 2 + qi;
      const int rl = i * 8 + sr8;               // 0..63
      gload16(qkv + (size_t)(kt * 64 + rl) * (3 * DM) + DM + hd * DHD + sch, Ks + i * 512);
      gload16(vT + (size_t)(hd * DHD + rl) * SEQ + kt * 64 + sch, Vs + i * 512);
    }
    __syncthreads();
    tile_step(qfB, accB, qbB, kt);
    if (kt <= qbA) tile_step(qfA, accA, qbA, kt);
  }

#pragma unroll
  for (int nt = 0; nt < 4; ++nt)
#pragma unroll
    for (int r = 0; r < 4; ++r) {
      const int col = hd * DHD + nt * 16 + lr;
      const int rowA = qbA * 64 + w * 16 + lg * 4 + r;
      obf[(size_t)rowA * DM + col] = f2bf(accA[nt][r]);
      const int rowB = qbB * 64 + w * 16 + lg * 4 + r;
      obf[(size_t)rowB * DM + col] = f2bf(accB[nt][r]);
    }
}

extern "C" void kernel_launch(void* const* d_in, const int* in_sizes, int n_in,
                              void* d_out, int out_size, void* d_ws, size_t ws_size,
                              hipStream_t stream) {
  const int*   x       = (const int*)d_in[0];
  const float* tok_emb = (const float*)d_in[1];
  const float* pos_emb = (const float*)d_in[2];
  const float* attn_ng = (const float*)d_in[3];
  const float* attn_nb = (const float*)d_in[4];
  const float* wqkv    = (const float*)d_in[5];
  const float* wo      = (const float*)d_in[6];
  const float* bo      = (const float*)d_in[7];
  const float* out_ng  = (const float*)d_in[8];
  const float* out_nb  = (const float*)d_in[9];
  const float* ff_ng   = (const float*)d_in[10];
  const float* ff_nb   = (const float*)d_in[11];
  const float* w1      = (const float*)d_in[12];
  const float* b1      = (const float*)d_in[13];
  const float* w2      = (const float*)d_in[14];
  const float* b2      = (const float*)d_in[15];
  const float* fin_g   = (const float*)d_in[16];
  const float* fin_b   = (const float*)d_in[17];
  const float* w_logit = (const float*)d_in[18];
  const float* b_logit = (const float*)d_in[19];
  float* out = (float*)d_out;

  char* ws = (char*)d_ws;
  size_t off = 0;
  auto alloc = [&](size_t bytes) -> void* {
    void* p = ws + off;
    off = (off + bytes + 255) & ~(size_t)255;
    return p;
  };
  unsigned short* wqkvT = (unsigned short*)alloc(4ull * 3072 * 1024 * 2);
  unsigned short* woT   = (unsigned short*)alloc(4ull * 1024 * 1024 * 2);
  unsigned short* w1T   = (unsigned short*)alloc(4ull * 4096 * 1024 * 2);
  unsigned short* w2T   = (unsigned short*)alloc(4ull * 1024 * 4096 * 2);
  unsigned short* wlogT = (unsigned short*)alloc((size_t)NV * 1024 * 2);
  float*          h     = (float*)alloc((size_t)SEQ * DM * 4);
  unsigned short* ybf   = (unsigned short*)alloc((size_t)SEQ * DM * 2);
  unsigned short* qkvbf = (unsigned short*)alloc((size_t)SEQ * 3 * DM * 2);
  unsigned short* vTb   = (unsigned short*)alloc((size_t)DM * SEQ * 2);
  unsigned short* obf   = (unsigned short*)alloc((size_t)SEQ * DM * 2);
  float*          tmpf  = (float*)alloc((size_t)SEQ * DM * 4);
  unsigned short* ffbf  = (unsigned short*)alloc((size_t)SEQ * FFD * 2);
  (void)ws_size; (void)in_sizes; (void)n_in; (void)out_size;

  const dim3 B(256);

  for (int l = 0; l < 4; ++l) {
    k_transpose_bf16<<<dim3(1024 / 32, 3072 / 32), B, 0, stream>>>(
        wqkv + (size_t)l * 1024 * 3072, wqkvT + (size_t)l * 3072 * 1024, 1024, 3072);
    k_transpose_bf16<<<dim3(1024 / 32, 1024 / 32), B, 0, stream>>>(
        wo + (size_t)l * 1024 * 1024, woT + (size_t)l * 1024 * 1024, 1024, 1024);
    k_transpose_bf16<<<dim3(1024 / 32, 4096 / 32), B, 0, stream>>>(
        w1 + (size_t)l * 1024 * 4096, w1T + (size_t)l * 4096 * 1024, 1024, 4096);
    k_transpose_bf16<<<dim3(4096 / 32, 1024 / 32), B, 0, stream>>>(
        w2 + (size_t)l * 4096 * 1024, w2T + (size_t)l * 1024 * 4096, 4096, 1024);
  }
  k_transpose_bf16<<<dim3(1024 / 32, NV / 32), B, 0, stream>>>(w_logit, wlogT, 1024, NV);

  k_embed<<<SEQ, B, 0, stream>>>(x, tok_emb, pos_emb, h);

  for (int l = 0; l < 4; ++l) {
    k_ln_bf16<<<SEQ, B, 0, stream>>>(h, attn_ng + l * DM, attn_nb + l * DM, ybf);
    k_gemm_bt<0><<<dim3(16 * (3072 / 128)), B, 0, stream>>>(
        ybf, wqkvT + (size_t)l * 3072 * 1024, nullptr, qkvbf, nullptr, nullptr, 3072, 1024, 16);
    k_vT<<<dim3(SEQ / 32, DM / 32), B, 0, stream>>>(qkvbf, vTb);
    k_rela_attn<<<dim3(16, NH), B, 0, stream>>>(qkvbf, vTb, obf);
    k_gemm_bt<1><<<dim3(16 * (1024 / 128)), B, 0, stream>>>(
        obf, woT + (size_t)l * 1024 * 1024, tmpf, nullptr, bo + l * DM, nullptr, 1024, 1024, 16);
    k_add_ln<<<SEQ, B, 0, stream>>>(h, tmpf, out_ng + l * DM, out_nb + l * DM);
    k_ln_bf16<<<SEQ, B, 0, stream>>>(h, ff_ng + l * DM, ff_nb + l * DM, ybf);
    k_gemm_bt<2><<<dim3(16 * (4096 / 128)), B, 0, stream>>>(
        ybf, w1T + (size_t)l * 4096 * 1024, nullptr, ffbf, b1 + l * FFD, nullptr, 4096, 1024, 16);
    k_gemm_bt<3><<<dim3(16 * (1024 / 128)), B, 0, stream>>>(
        ffbf, w2T + (size_t)l * 1024 * 4096, h, nullptr, b2 + l * DM, h, 1024, 4096, 16);
  }

  k_ln_bf16<<<SEQ, B, 0, stream>>>(h, fin_g, fin_b, ybf);
  k_gemm_bt<1><<<dim3(16 * (NV / 128)), B, 0, stream>>>(
      ybf, wlogT, out, nullptr, b_logit, nullptr, NV, 1024, 16);
}

// Round 3
// 1391.980 us; speedup vs baseline: 1.1173x; 1.0550x over previous
//
#include <hip/hip_runtime.h>
#include <hip/hip_bf16.h>
#include <math.h>

#define SEQ   2048
#define DM    1024
#define NH    16
#define DHD   64
#define FFD   4096
#define NV    32000

typedef __bf16 bf16x8 __attribute__((ext_vector_type(8)));
typedef float  f32x4  __attribute__((ext_vector_type(4)));

typedef __attribute__((address_space(1))) void* gas_ptr;
typedef __attribute__((address_space(3))) void* las_ptr;

static __device__ __forceinline__ void gload16(const void* g, void* l) {
  __builtin_amdgcn_global_load_lds((gas_ptr)g, (las_ptr)l, 16, 0, 0);
}

static __device__ __forceinline__ unsigned short f2bf(float f) {
  unsigned int x = __float_as_uint(f);
  return (unsigned short)((x + 0x7fffu + ((x >> 16) & 1u)) >> 16);
}

static __device__ __forceinline__ bf16x8 ld_frag(const unsigned short* p) {
  union { uint4 u; bf16x8 v; } r;
  r.u = *(const uint4*)p;
  return r.v;
}

// ---- transpose + f32->bf16 convert: out[n][k] = bf16(in[k][n]) ----
// 64x64 tiles, float4 global reads, transposed LDS (stride 65 -> 2-way max),
// uint4 (8xbf16) global writes.
__global__ __launch_bounds__(256)
void k_transpose_bf16(const float* __restrict__ in, unsigned short* __restrict__ out,
                      int K, int N) {
  __shared__ float tl[64 * 65];
  const int bk = blockIdx.x * 64, bn = blockIdx.y * 64;
  const int t = threadIdx.x;
  const int tx = t & 15, ty = t >> 4;
#pragma unroll
  for (int i = 0; i < 4; ++i) {
    const int r = i * 16 + ty;
    float4 v = *(const float4*)&in[(size_t)(bk + r) * N + bn + tx * 4];
    tl[(tx * 4 + 0) * 65 + r] = v.x;
    tl[(tx * 4 + 1) * 65 + r] = v.y;
    tl[(tx * 4 + 2) * 65 + r] = v.z;
    tl[(tx * 4 + 3) * 65 + r] = v.w;
  }
  __syncthreads();
#pragma unroll
  for (int j = 0; j < 2; ++j) {
    const int f = j * 256 + t;
    const int n = f >> 3, kc = (f & 7) * 8;
    union { unsigned short u[8]; uint4 v; } pk;
#pragma unroll
    for (int e = 0; e < 8; ++e) pk.u[e] = f2bf(tl[n * 65 + kc + e]);
    *(uint4*)&out[(size_t)(bn + n) * K + bk + kc] = pk.v;
  }
}

// ---- per-head V transpose: vT[h*64+d][s] = qkv[s][2*DM + h*64 + d] ----
__global__ __launch_bounds__(256)
void k_vT(const unsigned short* __restrict__ qkv, unsigned short* __restrict__ vT) {
  __shared__ unsigned short tile[32][33];
  const int bs = blockIdx.x * 32, bd = blockIdx.y * 32;
  const int tx = threadIdx.x & 31, ty = threadIdx.x >> 5;
#pragma unroll
  for (int r = ty; r < 32; r += 8)
    tile[r][tx] = qkv[(size_t)(bs + r) * (3 * DM) + 2 * DM + bd + tx];
  __syncthreads();
#pragma unroll
  for (int r = ty; r < 32; r += 8)
    vT[(size_t)(bd + r) * SEQ + bs + tx] = tile[tx][r];
}

// ---- embedding ----
__global__ __launch_bounds__(256)
void k_embed(const int* __restrict__ x, const float* __restrict__ tok,
             const float* __restrict__ pos, float* __restrict__ h) {
  const int row = blockIdx.x;
  const int d = threadIdx.x * 4;
  const int tk = x[row];
  float4 a = *(const float4*)(tok + (size_t)tk * DM + d);
  float4 p = *(const float4*)(pos + (size_t)row * DM + d);
  float4 o; o.x = a.x + p.x; o.y = a.y + p.y; o.z = a.z + p.z; o.w = a.w + p.w;
  *(float4*)(h + (size_t)row * DM + d) = o;
}

// ---- LayerNorm(in) -> bf16 out ----
__global__ __launch_bounds__(256)
void k_ln_bf16(const float* __restrict__ in, const float* __restrict__ g,
               const float* __restrict__ b, unsigned short* __restrict__ out) {
  const int row = blockIdx.x, t = threadIdx.x;
  float4 v = *(const float4*)(in + (size_t)row * DM + t * 4);
  float s = v.x + v.y + v.z + v.w;
  float q = v.x * v.x + v.y * v.y + v.z * v.z + v.w * v.w;
#pragma unroll
  for (int o = 32; o; o >>= 1) { s += __shfl_xor(s, o); q += __shfl_xor(q, o); }
  __shared__ float ls[4], lq[4];
  if ((t & 63) == 0) { ls[t >> 6] = s; lq[t >> 6] = q; }
  __syncthreads();
  s = ls[0] + ls[1] + ls[2] + ls[3];
  q = lq[0] + lq[1] + lq[2] + lq[3];
  const float mean = s * (1.f / DM);
  const float rstd = rsqrtf(q * (1.f / DM) - mean * mean + 1e-5f);
  float4 gg = *(const float4*)(g + t * 4);
  float4 bb = *(const float4*)(b + t * 4);
  ushort4 o4;
  o4.x = f2bf((v.x - mean) * rstd * gg.x + bb.x);
  o4.y = f2bf((v.y - mean) * rstd * gg.y + bb.y);
  o4.z = f2bf((v.z - mean) * rstd * gg.z + bb.z);
  o4.w = f2bf((v.w - mean) * rstd * gg.w + bb.w);
  *(ushort4*)(out + (size_t)row * DM + t * 4) = o4;
}

// ---- h += LayerNorm(in) ----
__global__ __launch_bounds__(256)
void k_add_ln(float* __restrict__ h, const float* __restrict__ in,
              const float* __restrict__ g, const float* __restrict__ b) {
  const int row = blockIdx.x, t = threadIdx.x;
  float4 v = *(const float4*)(in + (size_t)row * DM + t * 4);
  float s = v.x + v.y + v.z + v.w;
  float q = v.x * v.x + v.y * v.y + v.z * v.z + v.w * v.w;
#pragma unroll
  for (int o = 32; o; o >>= 1) { s += __shfl_xor(s, o); q += __shfl_xor(q, o); }
  __shared__ float ls[4], lq[4];
  if ((t & 63) == 0) { ls[t >> 6] = s; lq[t >> 6] = q; }
  __syncthreads();
  s = ls[0] + ls[1] + ls[2] + ls[3];
  q = lq[0] + lq[1] + lq[2] + lq[3];
  const float mean = s * (1.f / DM);
  const float rstd = rsqrtf(q * (1.f / DM) - mean * mean + 1e-5f);
  float4 gg = *(const float4*)(g + t * 4);
  float4 bb = *(const float4*)(b + t * 4);
  float4 hv = *(const float4*)(h + (size_t)row * DM + t * 4);
  hv.x += (v.x - mean) * rstd * gg.x + bb.x;
  hv.y += (v.y - mean) * rstd * gg.y + bb.y;
  hv.z += (v.z - mean) * rstd * gg.z + bb.z;
  hv.w += (v.w - mean) * rstd * gg.w + bb.w;
  *(float4*)(h + (size_t)row * DM + t * 4) = hv;
}

// ---- GEMM v2: C[M][N] = A[M][K](bf16) @ Bt[N][K](bf16)^T ----
// BM=128 BN=256 BK=64, 512 threads (8 waves: 2M x 4N), double-buffered LDS,
// counted vmcnt(6) (never 0 in main loop), raw s_barrier, setprio around MFMA.
// LDS layout: A: 2 x [128][64] (16KB each), B: 2 x [256][64] (32KB each) = 96KB.
// Chunk swizzle: LDS[row][c] holds global chunk (c ^ (row&7)).
template<int EPI>
__global__ __launch_bounds__(512, 1)
void k_gemm2(const unsigned short* __restrict__ A, const unsigned short* __restrict__ Bt,
             float* __restrict__ outF, unsigned short* __restrict__ outB,
             const float* __restrict__ bias, const float* __restrict__ res,
             int N, int K, int gm) {
  __shared__ __align__(16) unsigned short L[49152];
  const int nwg = gridDim.x, pid = blockIdx.x;
  const int qq = nwg >> 3, rr = nwg & 7;
  const int xcd = pid & 7, lo = pid >> 3;
  const int wg = ((xcd < rr) ? xcd * (qq + 1) : rr * (qq + 1) + (xcd - rr) * qq) + lo;
  const int bm = wg % gm, bn = wg / gm;
  const int t = threadIdx.x, lane = t & 63, w = t >> 6;
  const int wm = w >> 2, wn = w & 3, lr = lane & 15, lg = lane >> 4;

  // staging pointers
  const unsigned short* gA[2]; unsigned short* lA[2];
  const unsigned short* gB[4]; unsigned short* lB[4];
#pragma unroll
  for (int j = 0; j < 2; ++j) {
    const int f = j * 512 + t, row = f >> 3, c = f & 7;
    gA[j] = A + (size_t)(bm * 128 + row) * K + ((c ^ (row & 7)) << 3);
    lA[j] = L + f * 8;
  }
#pragma unroll
  for (int j = 0; j < 4; ++j) {
    const int f = j * 512 + t, row = f >> 3, c = f & 7;
    gB[j] = Bt + (size_t)(bn * 256 + row) * K + ((c ^ (row & 7)) << 3);
    lB[j] = L + 16384 + f * 8;
  }
  auto stage = [&](int k0, int c) {
#pragma unroll
    for (int j = 0; j < 2; ++j) gload16(gA[j] + k0, lA[j] + c * 8192);
#pragma unroll
    for (int j = 0; j < 4; ++j) gload16(gB[j] + k0, lB[j] + c * 16384);
  };

  // fragment LDS offsets (loop-invariant)
  int offA[4][2], offB[4][2];
#pragma unroll
  for (int mt = 0; mt < 4; ++mt)
#pragma unroll
    for (int ks = 0; ks < 2; ++ks) {
      const int rowA = wm * 64 + mt * 16 + lr;
      offA[mt][ks] = rowA * 64 + (((ks * 4 + lg) ^ (rowA & 7)) << 3);
      const int rowB = wn * 64 + mt * 16 + lr;
      offB[mt][ks] = rowB * 64 + (((ks * 4 + lg) ^ (rowB & 7)) << 3);
    }

  const f32x4 zero = {0.f, 0.f, 0.f, 0.f};
  f32x4 acc[4][4];
#pragma unroll
  for (int i = 0; i < 4; ++i)
#pragma unroll
    for (int j = 0; j < 4; ++j) acc[i][j] = zero;

  const int NT = K >> 6;
  stage(0, 0);
  if (NT > 1) stage(64, 1);

  for (int tt = 0; tt < NT; ++tt) {
    const int c = tt & 1;
    if (tt + 1 < NT) asm volatile("s_waitcnt vmcnt(6)" ::: "memory");
    else             asm volatile("s_waitcnt vmcnt(0)" ::: "memory");
    __builtin_amdgcn_s_barrier();
    const unsigned short* Ab = L + c * 8192;
    const unsigned short* Bb = L + 16384 + c * 16384;
    bf16x8 af[4][2], bfr[4][2];
#pragma unroll
    for (int mt = 0; mt < 4; ++mt)
#pragma unroll
      for (int ks = 0; ks < 2; ++ks) {
        af[mt][ks]  = ld_frag(Ab + offA[mt][ks]);
        bfr[mt][ks] = ld_frag(Bb + offB[mt][ks]);
      }
    __builtin_amdgcn_s_setprio(1);
#pragma unroll
    for (int mt = 0; mt < 4; ++mt)
#pragma unroll
      for (int nt = 0; nt < 4; ++nt)
#pragma unroll
        for (int ks = 0; ks < 2; ++ks)
          acc[mt][nt] = __builtin_amdgcn_mfma_f32_16x16x32_bf16(af[mt][ks], bfr[nt][ks], acc[mt][nt], 0, 0, 0);
    __builtin_amdgcn_s_setprio(0);
    asm volatile("s_waitcnt lgkmcnt(0)" ::: "memory");
    __builtin_amdgcn_s_barrier();
    if (tt + 2 < NT) stage((tt + 2) << 6, c);
  }

  const int rbase = bm * 128 + wm * 64;
  const int cbase = bn * 256 + wn * 64;
#pragma unroll
  for (int mt = 0; mt < 4; ++mt) {
#pragma unroll
    for (int nt = 0; nt < 4; ++nt) {
      const int col = cbase + nt * 16 + lr;
      float bv = 0.f;
      if constexpr (EPI != 0) bv = bias[col];
#pragma unroll
      for (int r = 0; r < 4; ++r) {
        const int row = rbase + mt * 16 + lg * 4 + r;
        float v = acc[mt][nt][r] + bv;
        if constexpr (EPI == 2) v = 0.5f * v * (1.f + erff(v * 0.70710678118f));
        if constexpr (EPI == 3) v += res[(size_t)row * N + col];
        if constexpr (EPI == 0 || EPI == 2) outB[(size_t)row * N + col] = f2bf(v);
        else                                outF[(size_t)row * N + col] = v;
      }
    }
  }
}

// ---- fused causal ReLA attention, balanced q-strip pairs ----
__global__ __launch_bounds__(256)
void k_rela_attn(const unsigned short* __restrict__ qkv,
                 const unsigned short* __restrict__ vT,
                 unsigned short* __restrict__ obf) {
  const int jb = blockIdx.x;      // 0..15
  const int hd = blockIdx.y;      // 0..15
  const int qbA = jb, qbB = 31 - jb;
  const int t = threadIdx.x, lane = t & 63, w = t >> 6;
  const int lr = lane & 15, lg = lane >> 4;

  __shared__ __align__(16) unsigned short Qs[128 * 64];
  __shared__ __align__(16) unsigned short Ks[64 * 64];
  __shared__ __align__(16) unsigned short Vs[64 * 64];
  __shared__ __align__(16) unsigned short Ps[4][16 * 72];

  const int sr8 = lane >> 3;
  const int sch = ((lane & 7) ^ sr8) << 3;

#pragma unroll
  for (int qi = 0; qi < 4; ++qi) {
    const int i = w * 4 + qi;
    const int rl = i * 8 + sr8;
    const int grow = (rl < 64) ? (qbA * 64 + rl) : (qbB * 64 + rl - 64);
    gload16(qkv + (size_t)grow * (3 * DM) + hd * DHD + sch, Qs + i * 512);
  }
  __syncthreads();

  bf16x8 qfA[2], qfB[2];
#pragma unroll
  for (int ks = 0; ks < 2; ++ks) {
    const int rowA = w * 16 + lr;
    qfA[ks] = ld_frag(&Qs[rowA * 64 + (((ks * 4 + lg) ^ (lr & 7)) << 3)]);
    const int rowB = 64 + w * 16 + lr;
    qfB[ks] = ld_frag(&Qs[rowB * 64 + (((ks * 4 + lg) ^ (lr & 7)) << 3)]);
  }

  const f32x4 zero = {0.f, 0.f, 0.f, 0.f};
  f32x4 accA[4], accB[4];
#pragma unroll
  for (int nt = 0; nt < 4; ++nt) { accA[nt] = zero; accB[nt] = zero; }

  auto tile_step = [&](const bf16x8* qf, f32x4* acc, int qb, int kt) {
    f32x4 sv[4];
#pragma unroll
    for (int nt = 0; nt < 4; ++nt) sv[nt] = zero;
#pragma unroll
    for (int ks = 0; ks < 2; ++ks)
#pragma unroll
      for (int nt = 0; nt < 4; ++nt) {
        bf16x8 kf = ld_frag(&Ks[(nt * 16 + lr) * 64 + (((ks * 4 + lg) ^ (lr & 7)) << 3)]);
        sv[nt] = __builtin_amdgcn_mfma_f32_16x16x32_bf16(qf[ks], kf, sv[nt], 0, 0, 0);
      }
    const bool diag = (kt == qb);
#pragma unroll
    for (int nt = 0; nt < 4; ++nt)
#pragma unroll
      for (int r = 0; r < 4; ++r) {
        float v = fmaxf(sv[nt][r], 0.f) * 0.125f;
        if (diag) {
          const int ii = w * 16 + lg * 4 + r;
          const int jj = nt * 16 + lr;
          if (jj > ii) v = 0.f;
        }
        Ps[w][(lg * 4 + r) * 72 + nt * 16 + lr] = f2bf(v);
      }
#pragma unroll
    for (int ks = 0; ks < 2; ++ks) {
      bf16x8 pf = ld_frag(&Ps[w][lr * 72 + ks * 32 + lg * 8]);
#pragma unroll
      for (int nt = 0; nt < 4; ++nt) {
        bf16x8 vf = ld_frag(&Vs[(nt * 16 + lr) * 64 + (((ks * 4 + lg) ^ (lr & 7)) << 3)]);
        acc[nt] = __builtin_amdgcn_mfma_f32_16x16x32_bf16(pf, vf, acc[nt], 0, 0, 0);
      }
    }
  };

  for (int kt = 0; kt <= qbB; ++kt) {
    __syncthreads();
#pragma unroll
    for (int qi = 0; qi < 2; ++qi) {
      const int i = w * 2 + qi;
      const int rl = i * 8 + sr8;
      gload16(qkv + (size_t)(kt * 64 + rl) * (3 * DM) + DM + hd * DHD + sch, Ks + i * 512);
      gload16(vT + (size_t)(hd * DHD + rl) * SEQ + kt * 64 + sch, Vs + i * 512);
    }
    __syncthreads();
    tile_step(qfB, accB, qbB, kt);
    if (kt <= qbA) tile_step(qfA, accA, qbA, kt);
  }

#pragma unroll
  for (int nt = 0; nt < 4; ++nt)
#pragma unroll
    for (int r = 0; r < 4; ++r) {
      const int col = hd * DHD + nt * 16 + lr;
      const int rowA = qbA * 64 + w * 16 + lg * 4 + r;
      obf[(size_t)rowA * DM + col] = f2bf(accA[nt][r]);
      const int rowB = qbB * 64 + w * 16 + lg * 4 + r;
      obf[(size_t)rowB * DM + col] = f2bf(accB[nt][r]);
    }
}

extern "C" void kernel_launch(void* const* d_in, const int* in_sizes, int n_in,
                              void* d_out, int out_size, void* d_ws, size_t ws_size,
                              hipStream_t stream) {
  const int*   x       = (const int*)d_in[0];
  const float* tok_emb = (const float*)d_in[1];
  const float* pos_emb = (const float*)d_in[2];
  const float* attn_ng = (const float*)d_in[3];
  const float* attn_nb = (const float*)d_in[4];
  const float* wqkv    = (const float*)d_in[5];
  const float* wo      = (const float*)d_in[6];
  const float* bo      = (const float*)d_in[7];
  const float* out_ng  = (const float*)d_in[8];
  const float* out_nb  = (const float*)d_in[9];
  const float* ff_ng   = (const float*)d_in[10];
  const float* ff_nb   = (const float*)d_in[11];
  const float* w1      = (const float*)d_in[12];
  const float* b1      = (const float*)d_in[13];
  const float* w2      = (const float*)d_in[14];
  const float* b2      = (const float*)d_in[15];
  const float* fin_g   = (const float*)d_in[16];
  const float* fin_b   = (const float*)d_in[17];
  const float* w_logit = (const float*)d_in[18];
  const float* b_logit = (const float*)d_in[19];
  float* out = (float*)d_out;

  char* ws = (char*)d_ws;
  size_t off = 0;
  auto alloc = [&](size_t bytes) -> void* {
    void* p = ws + off;
    off = (off + bytes + 255) & ~(size_t)255;
    return p;
  };
  unsigned short* wqkvT = (unsigned short*)alloc(4ull * 3072 * 1024 * 2);
  unsigned short* woT   = (unsigned short*)alloc(4ull * 1024 * 1024 * 2);
  unsigned short* w1T   = (unsigned short*)alloc(4ull * 4096 * 1024 * 2);
  unsigned short* w2T   = (unsigned short*)alloc(4ull * 1024 * 4096 * 2);
  unsigned short* wlogT = (unsigned short*)alloc((size_t)NV * 1024 * 2);
  float*          h     = (float*)alloc((size_t)SEQ * DM * 4);
  unsigned short* ybf   = (unsigned short*)alloc((size_t)SEQ * DM * 2);
  unsigned short* qkvbf = (unsigned short*)alloc((size_t)SEQ * 3 * DM * 2);
  unsigned short* vTb   = (unsigned short*)alloc((size_t)DM * SEQ * 2);
  unsigned short* obf   = (unsigned short*)alloc((size_t)SEQ * DM * 2);
  float*          tmpf  = (float*)alloc((size_t)SEQ * DM * 4);
  unsigned short* ffbf  = (unsigned short*)alloc((size_t)SEQ * FFD * 2);
  (void)ws_size; (void)in_sizes; (void)n_in; (void)out_size;

  const dim3 B(256);
  const dim3 G2(512);

  for (int l = 0; l < 4; ++l) {
    k_transpose_bf16<<<dim3(16, 48), B, 0, stream>>>(
        wqkv + (size_t)l * 1024 * 3072, wqkvT + (size_t)l * 3072 * 1024, 1024, 3072);
    k_transpose_bf16<<<dim3(16, 16), B, 0, stream>>>(
        wo + (size_t)l * 1024 * 1024, woT + (size_t)l * 1024 * 1024, 1024, 1024);
    k_transpose_bf16<<<dim3(16, 64), B, 0, stream>>>(
        w1 + (size_t)l * 1024 * 4096, w1T + (size_t)l * 4096 * 1024, 1024, 4096);
    k_transpose_bf16<<<dim3(64, 16), B, 0, stream>>>(
        w2 + (size_t)l * 4096 * 1024, w2T + (size_t)l * 1024 * 4096, 4096, 1024);
  }
  k_transpose_bf16<<<dim3(16, 500), B, 0, stream>>>(w_logit, wlogT, 1024, NV);

  k_embed<<<SEQ, B, 0, stream>>>(x, tok_emb, pos_emb, h);

  for (int l = 0; l < 4; ++l) {
    k_ln_bf16<<<SEQ, B, 0, stream>>>(h, attn_ng + l * DM, attn_nb + l * DM, ybf);
    k_gemm2<0><<<dim3(16 * (3072 / 256)), G2, 0, stream>>>(
        ybf, wqkvT + (size_t)l * 3072 * 1024, nullptr, qkvbf, nullptr, nullptr, 3072, 1024, 16);
    k_vT<<<dim3(SEQ / 32, DM / 32), B, 0, stream>>>(qkvbf, vTb);
    k_rela_attn<<<dim3(16, NH), B, 0, stream>>>(qkvbf, vTb, obf);
    k_gemm2<1><<<dim3(16 * (1024 / 256)), G2, 0, stream>>>(
        obf, woT + (size_t)l * 1024 * 1024, tmpf, nullptr, bo + l * DM, nullptr, 1024, 1024, 16);
    k_add_ln<<<SEQ, B, 0, stream>>>(h, tmpf, out_ng + l * DM, out_nb + l * DM);
    k_ln_bf16<<<SEQ, B, 0, stream>>>(h, ff_ng + l * DM, ff_nb + l * DM, ybf);
    k_gemm2<2><<<dim3(16 * (4096 / 256)), G2, 0, stream>>>(
        ybf, w1T + (size_t)l * 4096 * 1024, nullptr, ffbf, b1 + l * FFD, nullptr, 4096, 1024, 16);
    k_gemm2<3><<<dim3(16 * (1024 / 256)), G2, 0, stream>>>(
        ffbf, w2T + (size_t)l * 1024 * 4096, h, nullptr, b2 + l * DM, h, 1024, 4096, 16);
  }

  k_ln_bf16<<<SEQ, B, 0, stream>>>(h, fin_g, fin_b, ybf);
  k_gemm2<1><<<dim3(16 * (NV / 256)), G2, 0, stream>>>(
      ybf, wlogT, out, nullptr, b_logit, nullptr, NV, 1024, 16);
}

// Round 4
// 1140.062 us; speedup vs baseline: 1.3642x; 1.2210x over previous
//
#include <hip/hip_runtime.h>
#include <hip/hip_bf16.h>
#include <math.h>

#define SEQ   2048
#define DM    1024
#define NH    16
#define DHD   64
#define FFD   4096
#define NV    32000

typedef __bf16 bf16x8 __attribute__((ext_vector_type(8)));
typedef float  f32x4  __attribute__((ext_vector_type(4)));

typedef __attribute__((address_space(1))) void* gas_ptr;
typedef __attribute__((address_space(3))) void* las_ptr;

static __device__ __forceinline__ void gload16(const void* g, void* l) {
  __builtin_amdgcn_global_load_lds((gas_ptr)g, (las_ptr)l, 16, 0, 0);
}

static __device__ __forceinline__ unsigned short f2bf(float f) {
  unsigned int x = __float_as_uint(f);
  return (unsigned short)((x + 0x7fffu + ((x >> 16) & 1u)) >> 16);
}

static __device__ __forceinline__ bf16x8 ld_frag(const unsigned short* p) {
  union { uint4 u; bf16x8 v; } r;
  r.u = *(const uint4*)p;
  return r.v;
}

// ---- transpose + f32->bf16 convert, batched over blockIdx.z layers ----
__global__ __launch_bounds__(256)
void k_transpose_bf16(const float* __restrict__ in, unsigned short* __restrict__ out,
                      int K, int N, size_t lstride) {
  in  += (size_t)blockIdx.z * lstride;
  out += (size_t)blockIdx.z * lstride;
  __shared__ float tl[64 * 65];
  const int bk = blockIdx.x * 64, bn = blockIdx.y * 64;
  const int t = threadIdx.x;
  const int tx = t & 15, ty = t >> 4;
#pragma unroll
  for (int i = 0; i < 4; ++i) {
    const int r = i * 16 + ty;
    float4 v = *(const float4*)&in[(size_t)(bk + r) * N + bn + tx * 4];
    tl[(tx * 4 + 0) * 65 + r] = v.x;
    tl[(tx * 4 + 1) * 65 + r] = v.y;
    tl[(tx * 4 + 2) * 65 + r] = v.z;
    tl[(tx * 4 + 3) * 65 + r] = v.w;
  }
  __syncthreads();
#pragma unroll
  for (int j = 0; j < 2; ++j) {
    const int f = j * 256 + t;
    const int n = f >> 3, kc = (f & 7) * 8;
    union { unsigned short u[8]; uint4 v; } pk;
#pragma unroll
    for (int e = 0; e < 8; ++e) pk.u[e] = f2bf(tl[n * 65 + kc + e]);
    *(uint4*)&out[(size_t)(bn + n) * K + bk + kc] = pk.v;
  }
}

// ---- per-head V transpose ----
__global__ __launch_bounds__(256)
void k_vT(const unsigned short* __restrict__ qkv, unsigned short* __restrict__ vT) {
  __shared__ unsigned short tile[32][33];
  const int bs = blockIdx.x * 32, bd = blockIdx.y * 32;
  const int tx = threadIdx.x & 31, ty = threadIdx.x >> 5;
#pragma unroll
  for (int r = ty; r < 32; r += 8)
    tile[r][tx] = qkv[(size_t)(bs + r) * (3 * DM) + 2 * DM + bd + tx];
  __syncthreads();
#pragma unroll
  for (int r = ty; r < 32; r += 8)
    vT[(size_t)(bd + r) * SEQ + bs + tx] = tile[tx][r];
}

// ---- embedding ----
__global__ __launch_bounds__(256)
void k_embed(const int* __restrict__ x, const float* __restrict__ tok,
             const float* __restrict__ pos, float* __restrict__ h) {
  const int row = blockIdx.x;
  const int d = threadIdx.x * 4;
  const int tk = x[row];
  float4 a = *(const float4*)(tok + (size_t)tk * DM + d);
  float4 p = *(const float4*)(pos + (size_t)row * DM + d);
  float4 o; o.x = a.x + p.x; o.y = a.y + p.y; o.z = a.z + p.z; o.w = a.w + p.w;
  *(float4*)(h + (size_t)row * DM + d) = o;
}

// ---- LayerNorm(in) -> bf16 out ----
__global__ __launch_bounds__(256)
void k_ln_bf16(const float* __restrict__ in, const float* __restrict__ g,
               const float* __restrict__ b, unsigned short* __restrict__ out) {
  const int row = blockIdx.x, t = threadIdx.x;
  float4 v = *(const float4*)(in + (size_t)row * DM + t * 4);
  float s = v.x + v.y + v.z + v.w;
  float q = v.x * v.x + v.y * v.y + v.z * v.z + v.w * v.w;
#pragma unroll
  for (int o = 32; o; o >>= 1) { s += __shfl_xor(s, o); q += __shfl_xor(q, o); }
  __shared__ float ls[4], lq[4];
  if ((t & 63) == 0) { ls[t >> 6] = s; lq[t >> 6] = q; }
  __syncthreads();
  s = ls[0] + ls[1] + ls[2] + ls[3];
  q = lq[0] + lq[1] + lq[2] + lq[3];
  const float mean = s * (1.f / DM);
  const float rstd = rsqrtf(q * (1.f / DM) - mean * mean + 1e-5f);
  float4 gg = *(const float4*)(g + t * 4);
  float4 bb = *(const float4*)(b + t * 4);
  ushort4 o4;
  o4.x = f2bf((v.x - mean) * rstd * gg.x + bb.x);
  o4.y = f2bf((v.y - mean) * rstd * gg.y + bb.y);
  o4.z = f2bf((v.z - mean) * rstd * gg.z + bb.z);
  o4.w = f2bf((v.w - mean) * rstd * gg.w + bb.w);
  *(ushort4*)(out + (size_t)row * DM + t * 4) = o4;
}

// ---- h += LN1(in); out = bf16(LN2(h)) ----
__global__ __launch_bounds__(256)
void k_add_ln_ln(float* __restrict__ h, const float* __restrict__ in,
                 const float* __restrict__ g1, const float* __restrict__ b1,
                 const float* __restrict__ g2, const float* __restrict__ b2,
                 unsigned short* __restrict__ out) {
  const int row = blockIdx.x, t = threadIdx.x;
  __shared__ float ls[4], lq[4], ls2[4], lq2[4];
  float4 v = *(const float4*)(in + (size_t)row * DM + t * 4);
  float s = v.x + v.y + v.z + v.w;
  float q = v.x * v.x + v.y * v.y + v.z * v.z + v.w * v.w;
#pragma unroll
  for (int o = 32; o; o >>= 1) { s += __shfl_xor(s, o); q += __shfl_xor(q, o); }
  if ((t & 63) == 0) { ls[t >> 6] = s; lq[t >> 6] = q; }
  __syncthreads();
  s = ls[0] + ls[1] + ls[2] + ls[3];
  q = lq[0] + lq[1] + lq[2] + lq[3];
  const float mean = s * (1.f / DM);
  const float rstd = rsqrtf(q * (1.f / DM) - mean * mean + 1e-5f);
  float4 gg = *(const float4*)(g1 + t * 4);
  float4 bb = *(const float4*)(b1 + t * 4);
  float4 hv = *(const float4*)(h + (size_t)row * DM + t * 4);
  hv.x += (v.x - mean) * rstd * gg.x + bb.x;
  hv.y += (v.y - mean) * rstd * gg.y + bb.y;
  hv.z += (v.z - mean) * rstd * gg.z + bb.z;
  hv.w += (v.w - mean) * rstd * gg.w + bb.w;
  *(float4*)(h + (size_t)row * DM + t * 4) = hv;
  // second LN over hv
  float s2 = hv.x + hv.y + hv.z + hv.w;
  float q2 = hv.x * hv.x + hv.y * hv.y + hv.z * hv.z + hv.w * hv.w;
#pragma unroll
  for (int o = 32; o; o >>= 1) { s2 += __shfl_xor(s2, o); q2 += __shfl_xor(q2, o); }
  if ((t & 63) == 0) { ls2[t >> 6] = s2; lq2[t >> 6] = q2; }
  __syncthreads();
  s2 = ls2[0] + ls2[1] + ls2[2] + ls2[3];
  q2 = lq2[0] + lq2[1] + lq2[2] + lq2[3];
  const float mean2 = s2 * (1.f / DM);
  const float rstd2 = rsqrtf(q2 * (1.f / DM) - mean2 * mean2 + 1e-5f);
  float4 g2v = *(const float4*)(g2 + t * 4);
  float4 b2v = *(const float4*)(b2 + t * 4);
  ushort4 o4;
  o4.x = f2bf((hv.x - mean2) * rstd2 * g2v.x + b2v.x);
  o4.y = f2bf((hv.y - mean2) * rstd2 * g2v.y + b2v.y);
  o4.z = f2bf((hv.z - mean2) * rstd2 * g2v.z + b2v.z);
  o4.w = f2bf((hv.w - mean2) * rstd2 * g2v.w + b2v.w);
  *(ushort4*)(out + (size_t)row * DM + t * 4) = o4;
}

// ---- h += b2 + sum of 4 split-K slabs ----
__global__ __launch_bounds__(256)
void k_red_add(float* __restrict__ h, const float* __restrict__ sl,
               const float* __restrict__ b2) {
  const int row = blockIdx.x, d = threadIdx.x * 4;
  const size_t idx = (size_t)row * DM + d;
  float4 hv = *(const float4*)(h + idx);
  float4 bb = *(const float4*)(b2 + d);
  hv.x += bb.x; hv.y += bb.y; hv.z += bb.z; hv.w += bb.w;
#pragma unroll
  for (int c = 0; c < 4; ++c) {
    float4 p = *(const float4*)(sl + (size_t)c * SEQ * DM + idx);
    hv.x += p.x; hv.y += p.y; hv.z += p.z; hv.w += p.w;
  }
  *(float4*)(h + idx) = hv;
}

// ---- GEMM v2 (2-phase 128x256), kLen slab via blockIdx.y ----
// EPI: 0 bf16; 1 +bias f32; 2 +bias gelu bf16; 4 slab f32 partial (no bias)
template<int EPI>
__global__ __launch_bounds__(512, 1)
void k_gemm2(const unsigned short* __restrict__ A, const unsigned short* __restrict__ Bt,
             float* __restrict__ outF, unsigned short* __restrict__ outB,
             const float* __restrict__ bias, int N, int K, int kLen, int gm) {
  __shared__ __align__(16) unsigned short L[49152];
  const int nwg = gridDim.x, pid = blockIdx.x;
  const int qq = nwg >> 3, rr = nwg & 7;
  const int xcd = pid & 7, lo = pid >> 3;
  const int wg = ((xcd < rr) ? xcd * (qq + 1) : rr * (qq + 1) + (xcd - rr) * qq) + lo;
  const int bm = wg % gm, bn = wg / gm;
  const int kOff = blockIdx.y * kLen;
  const int t = threadIdx.x, lane = t & 63, w = t >> 6;
  const int wm = w >> 2, wn = w & 3, lr = lane & 15, lg = lane >> 4;

  const unsigned short* gA[2]; unsigned short* lA[2];
  const unsigned short* gB[4]; unsigned short* lB[4];
#pragma unroll
  for (int j = 0; j < 2; ++j) {
    const int f = j * 512 + t, row = f >> 3, c = f & 7;
    gA[j] = A + (size_t)(bm * 128 + row) * K + kOff + ((c ^ (row & 7)) << 3);
    lA[j] = L + f * 8;
  }
#pragma unroll
  for (int j = 0; j < 4; ++j) {
    const int f = j * 512 + t, row = f >> 3, c = f & 7;
    gB[j] = Bt + (size_t)(bn * 256 + row) * K + kOff + ((c ^ (row & 7)) << 3);
    lB[j] = L + 16384 + f * 8;
  }
  auto stage = [&](int k0, int c) {
#pragma unroll
    for (int j = 0; j < 2; ++j) gload16(gA[j] + k0, lA[j] + c * 8192);
#pragma unroll
    for (int j = 0; j < 4; ++j) gload16(gB[j] + k0, lB[j] + c * 16384);
  };

  int offA[4][2], offB[4][2];
#pragma unroll
  for (int mt = 0; mt < 4; ++mt)
#pragma unroll
    for (int ks = 0; ks < 2; ++ks) {
      const int rowA = wm * 64 + mt * 16 + lr;
      offA[mt][ks] = rowA * 64 + (((ks * 4 + lg) ^ (rowA & 7)) << 3);
      const int rowB = wn * 64 + mt * 16 + lr;
      offB[mt][ks] = rowB * 64 + (((ks * 4 + lg) ^ (rowB & 7)) << 3);
    }

  const f32x4 zero = {0.f, 0.f, 0.f, 0.f};
  f32x4 acc[4][4];
#pragma unroll
  for (int i = 0; i < 4; ++i)
#pragma unroll
    for (int j = 0; j < 4; ++j) acc[i][j] = zero;

  const int NT = kLen >> 6;
  stage(0, 0);
  if (NT > 1) stage(64, 1);

  for (int tt = 0; tt < NT; ++tt) {
    const int c = tt & 1;
    if (tt + 1 < NT) asm volatile("s_waitcnt vmcnt(6)" ::: "memory");
    else             asm volatile("s_waitcnt vmcnt(0)" ::: "memory");
    __builtin_amdgcn_s_barrier();
    const unsigned short* Ab = L + c * 8192;
    const unsigned short* Bb = L + 16384 + c * 16384;
    bf16x8 af[4][2], bfr[4][2];
#pragma unroll
    for (int mt = 0; mt < 4; ++mt)
#pragma unroll
      for (int ks = 0; ks < 2; ++ks) {
        af[mt][ks]  = ld_frag(Ab + offA[mt][ks]);
        bfr[mt][ks] = ld_frag(Bb + offB[mt][ks]);
      }
    __builtin_amdgcn_s_setprio(1);
#pragma unroll
    for (int mt = 0; mt < 4; ++mt)
#pragma unroll
      for (int nt = 0; nt < 4; ++nt)
#pragma unroll
        for (int ks = 0; ks < 2; ++ks)
          acc[mt][nt] = __builtin_amdgcn_mfma_f32_16x16x32_bf16(af[mt][ks], bfr[nt][ks], acc[mt][nt], 0, 0, 0);
    __builtin_amdgcn_s_setprio(0);
    asm volatile("s_waitcnt lgkmcnt(0)" ::: "memory");
    __builtin_amdgcn_s_barrier();
    if (tt + 2 < NT) stage((tt + 2) << 6, c);
  }

  const int rbase = bm * 128 + wm * 64;
  const int cbase = bn * 256 + wn * 64;
  float* outP = outF;
  if constexpr (EPI == 4) outP = outF + (size_t)blockIdx.y * SEQ * N;
#pragma unroll
  for (int mt = 0; mt < 4; ++mt) {
#pragma unroll
    for (int nt = 0; nt < 4; ++nt) {
      const int col = cbase + nt * 16 + lr;
      float bv = 0.f;
      if constexpr (EPI == 1 || EPI == 2) bv = bias[col];
#pragma unroll
      for (int r = 0; r < 4; ++r) {
        const int row = rbase + mt * 16 + lg * 4 + r;
        float v = acc[mt][nt][r] + bv;
        if constexpr (EPI == 2) v = 0.5f * v * (1.f + erff(v * 0.70710678118f));
        if constexpr (EPI == 0 || EPI == 2) outB[(size_t)row * N + col] = f2bf(v);
        else                                outP[(size_t)row * N + col] = v;
      }
    }
  }
}

// ---- GEMM v3: 8-phase 256x256x64, 8 waves (2Mx4N), counted vmcnt ----
// Quadrant order per K-tile: (0,0),(1,0),(1,1),(0,1). One half-tile staged per
// phase into the slot freed one phase earlier. Interleaved frag mapping:
// A-frag mt -> rows mt*32+wm*16 (mh = mt>>2 maps to LDS half), B-frag nt ->
// cols (nt&1)*64+(nt>>1)*128+wn*16. Per-phase vmcnt = [4,8,6,8,4,8,6,8].
// Epilogue stages clamp tile to NT-1 (dead slots) to keep counts exact.
__global__ __launch_bounds__(512, 1)
void k_gemm3(const unsigned short* __restrict__ A, const unsigned short* __restrict__ Bt,
             float* __restrict__ outF, const float* __restrict__ bias,
             int N, int K, int gm) {
  __shared__ __align__(16) unsigned short L[65536];
  const int nwg = gridDim.x, pid = blockIdx.x;
  const int qq = nwg >> 3, rr = nwg & 7;
  const int xcd = pid & 7, lo = pid >> 3;
  const int wg = ((xcd < rr) ? xcd * (qq + 1) : rr * (qq + 1) + (xcd - rr) * qq) + lo;
  const int bm = wg % gm, bn = wg / gm;
  const int t = threadIdx.x, lane = t & 63, w = t >> 6;
  const int wm = w >> 2, wn = w & 3, lr = lane & 15, lg = lane >> 4;
  const int NT = K >> 6;

  int offA[8][2], offB[4][2];
#pragma unroll
  for (int mt = 0; mt < 8; ++mt) {
    const int row = mt * 32 + wm * 16 + lr;
#pragma unroll
    for (int ks = 0; ks < 2; ++ks)
      offA[mt][ks] = row * 64 + (((ks * 4 + lg) ^ (row & 7)) << 3);
  }
#pragma unroll
  for (int nt = 0; nt < 4; ++nt) {
    const int row = ((nt & 1) << 6) + ((nt >> 1) << 7) + wn * 16 + lr;
#pragma unroll
    for (int ks = 0; ks < 2; ++ks)
      offB[nt][ks] = 16384 + row * 64 + (((ks * 4 + lg) ^ (row & 7)) << 3);
  }

  const unsigned short* gA = A  + (size_t)(bm * 256) * K;
  const unsigned short* gB = Bt + (size_t)(bn * 256) * K;

  auto stage_half = [&](int which, int tile, int half) {
    const int tt = (tile < NT) ? tile : (NT - 1);
    const unsigned short* g = which ? gB : gA;
    const int bufo = (tile & 1) << 15;
#pragma unroll
    for (int j = 0; j < 2; ++j) {
      const int f = (j << 9) + t;
      const int r = (half << 7) + (f >> 3);
      const int c = (f & 7) ^ (r & 7);
      gload16(g + (size_t)r * K + (tt << 6) + (c << 3),
              L + bufo + (which << 14) + (half << 13) + f * 8);
    }
  };

  f32x4 acc[8][4];
#pragma unroll
  for (int i = 0; i < 8; ++i)
#pragma unroll
    for (int j = 0; j < 4; ++j) acc[i][j] = (f32x4){0.f, 0.f, 0.f, 0.f};
  bf16x8 af[4][2], bfr[2][2];

  // prologue: virtual steady-state history [B0(0),A1(0),A0(0),B1(0),B0(1),A1(1)]
  stage_half(1, 0, 0); stage_half(0, 0, 1); stage_half(0, 0, 0);
  stage_half(1, 0, 1); stage_half(1, 1, 0); stage_half(0, 1, 1);

#define PHASE(VMS, LDA, LDB, MH, NH, BUFO, SW, ST, SH) do {                    \
  asm volatile("s_waitcnt vmcnt(" VMS ")" ::: "memory");                       \
  __builtin_amdgcn_s_barrier();                                                \
  if (LDA) {                                                                   \
    _Pragma("unroll") for (int mt = 0; mt < 4; ++mt)                           \
    _Pragma("unroll") for (int ks = 0; ks < 2; ++ks)                           \
      af[mt][ks] = ld_frag(L + (BUFO) + offA[(MH) * 4 + mt][ks]);              \
  }                                                                            \
  if (LDB) {                                                                   \
    _Pragma("unroll") for (int n = 0; n < 2; ++n)                              \
    _Pragma("unroll") for (int ks = 0; ks < 2; ++ks)                           \
      bfr[n][ks] = ld_frag(L + (BUFO) + offB[(NH) * 2 + n][ks]);               \
  }                                                                            \
  stage_half((SW), (ST), (SH));                                                \
  asm volatile("s_waitcnt lgkmcnt(0)" ::: "memory");                           \
  __builtin_amdgcn_sched_barrier(0);                                           \
  __builtin_amdgcn_s_setprio(1);                                               \
  _Pragma("unroll") for (int mt = 0; mt < 4; ++mt)                             \
  _Pragma("unroll") for (int n = 0; n < 2; ++n)                                \
  _Pragma("unroll") for (int ks = 0; ks < 2; ++ks)                             \
    acc[(MH) * 4 + mt][(NH) * 2 + n] = __builtin_amdgcn_mfma_f32_16x16x32_bf16(\
        af[mt][ks], bfr[n][ks], acc[(MH) * 4 + mt][(NH) * 2 + n], 0, 0, 0);    \
  __builtin_amdgcn_s_setprio(0);                                               \
} while (0)

  for (int I = 0; I < (NT >> 1); ++I) {
    const int T = I << 1;
    PHASE("4", 1, 1, 0, 0, 0,     0, T + 1, 0);
    PHASE("8", 1, 0, 1, 0, 0,     1, T + 1, 1);
    PHASE("6", 0, 1, 1, 1, 0,     1, T + 2, 0);
    PHASE("8", 1, 0, 0, 1, 0,     0, T + 2, 1);
    PHASE("4", 1, 1, 0, 0, 32768, 0, T + 2, 0);
    PHASE("8", 1, 0, 1, 0, 32768, 1, T + 2, 1);
    PHASE("6", 0, 1, 1, 1, 32768, 1, T + 3, 0);
    PHASE("8", 1, 0, 0, 1, 32768, 0, T + 3, 1);
  }
#undef PHASE

#pragma unroll
  for (int mt = 0; mt < 8; ++mt) {
    const int row0 = bm * 256 + mt * 32 + wm * 16 + lg * 4;
#pragma unroll
    for (int nt = 0; nt < 4; ++nt) {
      const int col = bn * 256 + ((nt & 1) << 6) + ((nt >> 1) << 7) + wn * 16 + lr;
      const float bv = bias[col];
#pragma unroll
      for (int r = 0; r < 4; ++r)
        outF[(size_t)(row0 + r) * N + col] = acc[mt][nt][r] + bv;
    }
  }
}

// ---- fused causal ReLA attention, balanced q-strip pairs ----
__global__ __launch_bounds__(256)
void k_rela_attn(const unsigned short* __restrict__ qkv,
                 const unsigned short* __restrict__ vT,
                 unsigned short* __restrict__ obf) {
  const int jb = blockIdx.x;
  const int hd = blockIdx.y;
  const int qbA = jb, qbB = 31 - jb;
  const int t = threadIdx.x, lane = t & 63, w = t >> 6;
  const int lr = lane & 15, lg = lane >> 4;

  __shared__ __align__(16) unsigned short Qs[128 * 64];
  __shared__ __align__(16) unsigned short Ks[64 * 64];
  __shared__ __align__(16) unsigned short Vs[64 * 64];
  __shared__ __align__(16) unsigned short Ps[4][16 * 72];

  const int sr8 = lane >> 3;
  const int sch = ((lane & 7) ^ sr8) << 3;

#pragma unroll
  for (int qi = 0; qi < 4; ++qi) {
    const int i = w * 4 + qi;
    const int rl = i * 8 + sr8;
    const int grow = (rl < 64) ? (qbA * 64 + rl) : (qbB * 64 + rl - 64);
    gload16(qkv + (size_t)grow * (3 * DM) + hd * DHD + sch, Qs + i * 512);
  }
  __syncthreads();

  bf16x8 qfA[2], qfB[2];
#pragma unroll
  for (int ks = 0; ks < 2; ++ks) {
    const int rowA = w * 16 + lr;
    qfA[ks] = ld_frag(&Qs[rowA * 64 + (((ks * 4 + lg) ^ (lr & 7)) << 3)]);
    const int rowB = 64 + w * 16 + lr;
    qfB[ks] = ld_frag(&Qs[rowB * 64 + (((ks * 4 + lg) ^ (lr & 7)) << 3)]);
  }

  const f32x4 zero = {0.f, 0.f, 0.f, 0.f};
  f32x4 accA[4], accB[4];
#pragma unroll
  for (int nt = 0; nt < 4; ++nt) { accA[nt] = zero; accB[nt] = zero; }

  auto tile_step = [&](const bf16x8* qf, f32x4* acc, int qb, int kt) {
    f32x4 sv[4];
#pragma unroll
    for (int nt = 0; nt < 4; ++nt) sv[nt] = zero;
#pragma unroll
    for (int ks = 0; ks < 2; ++ks)
#pragma unroll
      for (int nt = 0; nt < 4; ++nt) {
        bf16x8 kf = ld_frag(&Ks[(nt * 16 + lr) * 64 + (((ks * 4 + lg) ^ (lr & 7)) << 3)]);
        sv[nt] = __builtin_amdgcn_mfma_f32_16x16x32_bf16(qf[ks], kf, sv[nt], 0, 0, 0);
      }
    const bool diag = (kt == qb);
#pragma unroll
    for (int nt = 0; nt < 4; ++nt)
#pragma unroll
      for (int r = 0; r < 4; ++r) {
        float v = fmaxf(sv[nt][r], 0.f) * 0.125f;
        if (diag) {
          const int ii = w * 16 + lg * 4 + r;
          const int jj = nt * 16 + lr;
          if (jj > ii) v = 0.f;
        }
        Ps[w][(lg * 4 + r) * 72 + nt * 16 + lr] = f2bf(v);
      }
#pragma unroll
    for (int ks = 0; ks < 2; ++ks) {
      bf16x8 pf = ld_frag(&Ps[w][lr * 72 + ks * 32 + lg * 8]);
#pragma unroll
      for (int nt = 0; nt < 4; ++nt) {
        bf16x8 vf = ld_frag(&Vs[(nt * 16 + lr) * 64 + (((ks * 4 + lg) ^ (lr & 7)) << 3)]);
        acc[nt] = __builtin_amdgcn_mfma_f32_16x16x32_bf16(pf, vf, acc[nt], 0, 0, 0);
      }
    }
  };

  for (int kt = 0; kt <= qbB; ++kt) {
    __syncthreads();
#pragma unroll
    for (int qi = 0; qi < 2; ++qi) {
      const int i = w * 2 + qi;
      const int rl = i * 8 + sr8;
      gload16(qkv + (size_t)(kt * 64 + rl) * (3 * DM) + DM + hd * DHD + sch, Ks + i * 512);
      gload16(vT + (size_t)(hd * DHD + rl) * SEQ + kt * 64 + sch, Vs + i * 512);
    }
    __syncthreads();
    tile_step(qfB, accB, qbB, kt);
    if (kt <= qbA) tile_step(qfA, accA, qbA, kt);
  }

#pragma unroll
  for (int nt = 0; nt < 4; ++nt)
#pragma unroll
    for (int r = 0; r < 4; ++r) {
      const int col = hd * DHD + nt * 16 + lr;
      const int rowA = qbA * 64 + w * 16 + lg * 4 + r;
      obf[(size_t)rowA * DM + col] = f2bf(accA[nt][r]);
      const int rowB = qbB * 64 + w * 16 + lg * 4 + r;
      obf[(size_t)rowB * DM + col] = f2bf(accB[nt][r]);
    }
}

extern "C" void kernel_launch(void* const* d_in, const int* in_sizes, int n_in,
                              void* d_out, int out_size, void* d_ws, size_t ws_size,
                              hipStream_t stream) {
  const int*   x       = (const int*)d_in[0];
  const float* tok_emb = (const float*)d_in[1];
  const float* pos_emb = (const float*)d_in[2];
  const float* attn_ng = (const float*)d_in[3];
  const float* attn_nb = (const float*)d_in[4];
  const float* wqkv    = (const float*)d_in[5];
  const float* wo      = (const float*)d_in[6];
  const float* bo      = (const float*)d_in[7];
  const float* out_ng  = (const float*)d_in[8];
  const float* out_nb  = (const float*)d_in[9];
  const float* ff_ng   = (const float*)d_in[10];
  const float* ff_nb   = (const float*)d_in[11];
  const float* w1      = (const float*)d_in[12];
  const float* b1      = (const float*)d_in[13];
  const float* w2      = (const float*)d_in[14];
  const float* b2      = (const float*)d_in[15];
  const float* fin_g   = (const float*)d_in[16];
  const float* fin_b   = (const float*)d_in[17];
  const float* w_logit = (const float*)d_in[18];
  const float* b_logit = (const float*)d_in[19];
  float* out = (float*)d_out;

  char* ws = (char*)d_ws;
  size_t off = 0;
  auto alloc = [&](size_t bytes) -> void* {
    void* p = ws + off;
    off = (off + bytes + 255) & ~(size_t)255;
    return p;
  };
  unsigned short* wqkvT = (unsigned short*)alloc(4ull * 3072 * 1024 * 2);
  unsigned short* woT   = (unsigned short*)alloc(4ull * 1024 * 1024 * 2);
  unsigned short* w1T   = (unsigned short*)alloc(4ull * 4096 * 1024 * 2);
  unsigned short* w2T   = (unsigned short*)alloc(4ull * 1024 * 4096 * 2);
  unsigned short* wlogT = (unsigned short*)alloc((size_t)NV * 1024 * 2);
  float*          h     = (float*)alloc((size_t)SEQ * DM * 4);
  unsigned short* ybf   = (unsigned short*)alloc((size_t)SEQ * DM * 2);
  unsigned short* qkvbf = (unsigned short*)alloc((size_t)SEQ * 3 * DM * 2);
  unsigned short* vTb   = (unsigned short*)alloc((size_t)DM * SEQ * 2);
  unsigned short* obf   = (unsigned short*)alloc((size_t)SEQ * DM * 2);
  float*          tmpf  = (float*)alloc((size_t)SEQ * DM * 4);
  unsigned short* ffbf  = (unsigned short*)alloc((size_t)SEQ * FFD * 2);
  float*          slabs = (float*)alloc(4ull * SEQ * DM * 4);
  (void)ws_size; (void)in_sizes; (void)n_in; (void)out_size;

  const dim3 B(256);
  const dim3 G2(512);

  // batched weight transposes (z = layer)
  k_transpose_bf16<<<dim3(16, 48, 4), B, 0, stream>>>(wqkv, wqkvT, 1024, 3072, (size_t)1024 * 3072);
  k_transpose_bf16<<<dim3(16, 16, 4), B, 0, stream>>>(wo, woT, 1024, 1024, (size_t)1024 * 1024);
  k_transpose_bf16<<<dim3(16, 64, 4), B, 0, stream>>>(w1, w1T, 1024, 4096, (size_t)1024 * 4096);
  k_transpose_bf16<<<dim3(64, 16, 4), B, 0, stream>>>(w2, w2T, 4096, 1024, (size_t)4096 * 1024);
  k_transpose_bf16<<<dim3(16, 500, 1), B, 0, stream>>>(w_logit, wlogT, 1024, NV, 0);

  k_embed<<<SEQ, B, 0, stream>>>(x, tok_emb, pos_emb, h);

  for (int l = 0; l < 4; ++l) {
    k_ln_bf16<<<SEQ, B, 0, stream>>>(h, attn_ng + l * DM, attn_nb + l * DM, ybf);
    k_gemm2<0><<<dim3(192), G2, 0, stream>>>(
        ybf, wqkvT + (size_t)l * 3072 * 1024, nullptr, qkvbf, nullptr, 3072, 1024, 1024, 16);
    k_vT<<<dim3(SEQ / 32, DM / 32), B, 0, stream>>>(qkvbf, vTb);
    k_rela_attn<<<dim3(16, NH), B, 0, stream>>>(qkvbf, vTb, obf);
    k_gemm2<1><<<dim3(64), G2, 0, stream>>>(
        obf, woT + (size_t)l * 1024 * 1024, tmpf, nullptr, bo + l * DM, 1024, 1024, 1024, 16);
    k_add_ln_ln<<<SEQ, B, 0, stream>>>(h, tmpf, out_ng + l * DM, out_nb + l * DM,
                                       ff_ng + l * DM, ff_nb + l * DM, ybf);
    k_gemm2<2><<<dim3(256), G2, 0, stream>>>(
        ybf, w1T + (size_t)l * 4096 * 1024, nullptr, ffbf, b1 + l * FFD, 4096, 1024, 1024, 16);
    k_gemm2<4><<<dim3(64, 4), G2, 0, stream>>>(
        ffbf, w2T + (size_t)l * 1024 * 4096, slabs, nullptr, nullptr, 1024, 4096, 1024, 16);
    k_red_add<<<SEQ, B, 0, stream>>>(h, slabs, b2 + l * DM);
  }

  k_ln_bf16<<<SEQ, B, 0, stream>>>(h, fin_g, fin_b, ybf);
  k_gemm3<<<dim3(1000), G2, 0, stream>>>(ybf, wlogT, out, b_logit, NV, 1024, 8);
}

// Round 5
// 1087.027 us; speedup vs baseline: 1.4308x; 1.0488x over previous
//
#include <hip/hip_runtime.h>
#include <hip/hip_bf16.h>
#include <math.h>

#define SEQ   2048
#define DM    1024
#define NH    16
#define DHD   64
#define FFD   4096
#define NV    32000

typedef __bf16 bf16x8 __attribute__((ext_vector_type(8)));
typedef float  f32x4  __attribute__((ext_vector_type(4)));

typedef __attribute__((address_space(1))) void* gas_ptr;
typedef __attribute__((address_space(3))) void* las_ptr;

static __device__ __forceinline__ void gload16(const void* g, void* l) {
  __builtin_amdgcn_global_load_lds((gas_ptr)g, (las_ptr)l, 16, 0, 0);
}

static __device__ __forceinline__ unsigned short f2bf(float f) {
  unsigned int x = __float_as_uint(f);
  return (unsigned short)((x + 0x7fffu + ((x >> 16) & 1u)) >> 16);
}

static __device__ __forceinline__ bf16x8 ld_frag(const unsigned short* p) {
  union { uint4 u; bf16x8 v; } r;
  r.u = *(const uint4*)p;
  return r.v;
}

// ---- transpose + f32->bf16 convert, batched over blockIdx.z layers ----
__global__ __launch_bounds__(256)
void k_transpose_bf16(const float* __restrict__ in, unsigned short* __restrict__ out,
                      int K, int N, size_t lstride) {
  in  += (size_t)blockIdx.z * lstride;
  out += (size_t)blockIdx.z * lstride;
  __shared__ float tl[64 * 65];
  const int bk = blockIdx.x * 64, bn = blockIdx.y * 64;
  const int t = threadIdx.x;
  const int tx = t & 15, ty = t >> 4;
#pragma unroll
  for (int i = 0; i < 4; ++i) {
    const int r = i * 16 + ty;
    float4 v = *(const float4*)&in[(size_t)(bk + r) * N + bn + tx * 4];
    tl[(tx * 4 + 0) * 65 + r] = v.x;
    tl[(tx * 4 + 1) * 65 + r] = v.y;
    tl[(tx * 4 + 2) * 65 + r] = v.z;
    tl[(tx * 4 + 3) * 65 + r] = v.w;
  }
  __syncthreads();
#pragma unroll
  for (int j = 0; j < 2; ++j) {
    const int f = j * 256 + t;
    const int n = f >> 3, kc = (f & 7) * 8;
    union { unsigned short u[8]; uint4 v; } pk;
#pragma unroll
    for (int e = 0; e < 8; ++e) pk.u[e] = f2bf(tl[n * 65 + kc + e]);
    *(uint4*)&out[(size_t)(bn + n) * K + bk + kc] = pk.v;
  }
}

// ---- per-head V transpose ----
__global__ __launch_bounds__(256)
void k_vT(const unsigned short* __restrict__ qkv, unsigned short* __restrict__ vT) {
  __shared__ unsigned short tile[32][33];
  const int bs = blockIdx.x * 32, bd = blockIdx.y * 32;
  const int tx = threadIdx.x & 31, ty = threadIdx.x >> 5;
#pragma unroll
  for (int r = ty; r < 32; r += 8)
    tile[r][tx] = qkv[(size_t)(bs + r) * (3 * DM) + 2 * DM + bd + tx];
  __syncthreads();
#pragma unroll
  for (int r = ty; r < 32; r += 8)
    vT[(size_t)(bd + r) * SEQ + bs + tx] = tile[tx][r];
}

// ---- embedding ----
__global__ __launch_bounds__(256)
void k_embed(const int* __restrict__ x, const float* __restrict__ tok,
             const float* __restrict__ pos, float* __restrict__ h) {
  const int row = blockIdx.x;
  const int d = threadIdx.x * 4;
  const int tk = x[row];
  float4 a = *(const float4*)(tok + (size_t)tk * DM + d);
  float4 p = *(const float4*)(pos + (size_t)row * DM + d);
  float4 o; o.x = a.x + p.x; o.y = a.y + p.y; o.z = a.z + p.z; o.w = a.w + p.w;
  *(float4*)(h + (size_t)row * DM + d) = o;
}

// ---- LayerNorm(in) -> bf16 out ----
__global__ __launch_bounds__(256)
void k_ln_bf16(const float* __restrict__ in, const float* __restrict__ g,
               const float* __restrict__ b, unsigned short* __restrict__ out) {
  const int row = blockIdx.x, t = threadIdx.x;
  float4 v = *(const float4*)(in + (size_t)row * DM + t * 4);
  float s = v.x + v.y + v.z + v.w;
  float q = v.x * v.x + v.y * v.y + v.z * v.z + v.w * v.w;
#pragma unroll
  for (int o = 32; o; o >>= 1) { s += __shfl_xor(s, o); q += __shfl_xor(q, o); }
  __shared__ float ls[4], lq[4];
  if ((t & 63) == 0) { ls[t >> 6] = s; lq[t >> 6] = q; }
  __syncthreads();
  s = ls[0] + ls[1] + ls[2] + ls[3];
  q = lq[0] + lq[1] + lq[2] + lq[3];
  const float mean = s * (1.f / DM);
  const float rstd = rsqrtf(q * (1.f / DM) - mean * mean + 1e-5f);
  float4 gg = *(const float4*)(g + t * 4);
  float4 bb = *(const float4*)(b + t * 4);
  ushort4 o4;
  o4.x = f2bf((v.x - mean) * rstd * gg.x + bb.x);
  o4.y = f2bf((v.y - mean) * rstd * gg.y + bb.y);
  o4.z = f2bf((v.z - mean) * rstd * gg.z + bb.z);
  o4.w = f2bf((v.w - mean) * rstd * gg.w + bb.w);
  *(ushort4*)(out + (size_t)row * DM + t * 4) = o4;
}

// ---- h += LN1(in); out = bf16(LN2(h)) ----
__global__ __launch_bounds__(256)
void k_add_ln_ln(float* __restrict__ h, const float* __restrict__ in,
                 const float* __restrict__ g1, const float* __restrict__ b1,
                 const float* __restrict__ g2, const float* __restrict__ b2,
                 unsigned short* __restrict__ out) {
  const int row = blockIdx.x, t = threadIdx.x;
  __shared__ float ls[4], lq[4], ls2[4], lq2[4];
  float4 v = *(const float4*)(in + (size_t)row * DM + t * 4);
  float s = v.x + v.y + v.z + v.w;
  float q = v.x * v.x + v.y * v.y + v.z * v.z + v.w * v.w;
#pragma unroll
  for (int o = 32; o; o >>= 1) { s += __shfl_xor(s, o); q += __shfl_xor(q, o); }
  if ((t & 63) == 0) { ls[t >> 6] = s; lq[t >> 6] = q; }
  __syncthreads();
  s = ls[0] + ls[1] + ls[2] + ls[3];
  q = lq[0] + lq[1] + lq[2] + lq[3];
  const float mean = s * (1.f / DM);
  const float rstd = rsqrtf(q * (1.f / DM) - mean * mean + 1e-5f);
  float4 gg = *(const float4*)(g1 + t * 4);
  float4 bb = *(const float4*)(b1 + t * 4);
  float4 hv = *(const float4*)(h + (size_t)row * DM + t * 4);
  hv.x += (v.x - mean) * rstd * gg.x + bb.x;
  hv.y += (v.y - mean) * rstd * gg.y + bb.y;
  hv.z += (v.z - mean) * rstd * gg.z + bb.z;
  hv.w += (v.w - mean) * rstd * gg.w + bb.w;
  *(float4*)(h + (size_t)row * DM + t * 4) = hv;
  float s2 = hv.x + hv.y + hv.z + hv.w;
  float q2 = hv.x * hv.x + hv.y * hv.y + hv.z * hv.z + hv.w * hv.w;
#pragma unroll
  for (int o = 32; o; o >>= 1) { s2 += __shfl_xor(s2, o); q2 += __shfl_xor(q2, o); }
  if ((t & 63) == 0) { ls2[t >> 6] = s2; lq2[t >> 6] = q2; }
  __syncthreads();
  s2 = ls2[0] + ls2[1] + ls2[2] + ls2[3];
  q2 = lq2[0] + lq2[1] + lq2[2] + lq2[3];
  const float mean2 = s2 * (1.f / DM);
  const float rstd2 = rsqrtf(q2 * (1.f / DM) - mean2 * mean2 + 1e-5f);
  float4 g2v = *(const float4*)(g2 + t * 4);
  float4 b2v = *(const float4*)(b2 + t * 4);
  ushort4 o4;
  o4.x = f2bf((hv.x - mean2) * rstd2 * g2v.x + b2v.x);
  o4.y = f2bf((hv.y - mean2) * rstd2 * g2v.y + b2v.y);
  o4.z = f2bf((hv.z - mean2) * rstd2 * g2v.z + b2v.z);
  o4.w = f2bf((hv.w - mean2) * rstd2 * g2v.w + b2v.w);
  *(ushort4*)(out + (size_t)row * DM + t * 4) = o4;
}

// ---- h += b2 + sum of 4 split-K slabs ----
__global__ __launch_bounds__(256)
void k_red_add(float* __restrict__ h, const float* __restrict__ sl,
               const float* __restrict__ b2) {
  const int row = blockIdx.x, d = threadIdx.x * 4;
  const size_t idx = (size_t)row * DM + d;
  float4 hv = *(const float4*)(h + idx);
  float4 bb = *(const float4*)(b2 + d);
  hv.x += bb.x; hv.y += bb.y; hv.z += bb.z; hv.w += bb.w;
#pragma unroll
  for (int c = 0; c < 4; ++c) {
    float4 p = *(const float4*)(sl + (size_t)c * SEQ * DM + idx);
    hv.x += p.x; hv.y += p.y; hv.z += p.z; hv.w += p.w;
  }
  *(float4*)(h + idx) = hv;
}

// ---- GEMM v2 (2-phase 128x256), kLen slab via blockIdx.y ----
template<int EPI>
__global__ __launch_bounds__(512, 1)
void k_gemm2(const unsigned short* __restrict__ A, const unsigned short* __restrict__ Bt,
             float* __restrict__ outF, unsigned short* __restrict__ outB,
             const float* __restrict__ bias, int N, int K, int kLen, int gm) {
  __shared__ __align__(16) unsigned short L[49152];
  const int nwg = gridDim.x, pid = blockIdx.x;
  const int qq = nwg >> 3, rr = nwg & 7;
  const int xcd = pid & 7, lo = pid >> 3;
  const int wg = ((xcd < rr) ? xcd * (qq + 1) : rr * (qq + 1) + (xcd - rr) * qq) + lo;
  const int bm = wg % gm, bn = wg / gm;
  const int kOff = blockIdx.y * kLen;
  const int t = threadIdx.x, lane = t & 63, w = t >> 6;
  const int wm = w >> 2, wn = w & 3, lr = lane & 15, lg = lane >> 4;

  const unsigned short* gA[2]; unsigned short* lA[2];
  const unsigned short* gB[4]; unsigned short* lB[4];
#pragma unroll
  for (int j = 0; j < 2; ++j) {
    const int f = j * 512 + t, row = f >> 3, c = f & 7;
    gA[j] = A + (size_t)(bm * 128 + row) * K + kOff + ((c ^ (row & 7)) << 3);
    lA[j] = L + f * 8;
  }
#pragma unroll
  for (int j = 0; j < 4; ++j) {
    const int f = j * 512 + t, row = f >> 3, c = f & 7;
    gB[j] = Bt + (size_t)(bn * 256 + row) * K + kOff + ((c ^ (row & 7)) << 3);
    lB[j] = L + 16384 + f * 8;
  }
  auto stage = [&](int k0, int c) {
#pragma unroll
    for (int j = 0; j < 2; ++j) gload16(gA[j] + k0, lA[j] + c * 8192);
#pragma unroll
    for (int j = 0; j < 4; ++j) gload16(gB[j] + k0, lB[j] + c * 16384);
  };

  int offA[4][2], offB[4][2];
#pragma unroll
  for (int mt = 0; mt < 4; ++mt)
#pragma unroll
    for (int ks = 0; ks < 2; ++ks) {
      const int rowA = wm * 64 + mt * 16 + lr;
      offA[mt][ks] = rowA * 64 + (((ks * 4 + lg) ^ (rowA & 7)) << 3);
      const int rowB = wn * 64 + mt * 16 + lr;
      offB[mt][ks] = rowB * 64 + (((ks * 4 + lg) ^ (rowB & 7)) << 3);
    }

  const f32x4 zero = {0.f, 0.f, 0.f, 0.f};
  f32x4 acc[4][4];
#pragma unroll
  for (int i = 0; i < 4; ++i)
#pragma unroll
    for (int j = 0; j < 4; ++j) acc[i][j] = zero;

  const int NT = kLen >> 6;
  stage(0, 0);
  if (NT > 1) stage(64, 1);

  for (int tt = 0; tt < NT; ++tt) {
    const int c = tt & 1;
    if (tt + 1 < NT) asm volatile("s_waitcnt vmcnt(6)" ::: "memory");
    else             asm volatile("s_waitcnt vmcnt(0)" ::: "memory");
    __builtin_amdgcn_s_barrier();
    const unsigned short* Ab = L + c * 8192;
    const unsigned short* Bb = L + 16384 + c * 16384;
    bf16x8 af[4][2], bfr[4][2];
#pragma unroll
    for (int mt = 0; mt < 4; ++mt)
#pragma unroll
      for (int ks = 0; ks < 2; ++ks) {
        af[mt][ks]  = ld_frag(Ab + offA[mt][ks]);
        bfr[mt][ks] = ld_frag(Bb + offB[mt][ks]);
      }
    __builtin_amdgcn_s_setprio(1);
#pragma unroll
    for (int mt = 0; mt < 4; ++mt)
#pragma unroll
      for (int nt = 0; nt < 4; ++nt)
#pragma unroll
        for (int ks = 0; ks < 2; ++ks)
          acc[mt][nt] = __builtin_amdgcn_mfma_f32_16x16x32_bf16(af[mt][ks], bfr[nt][ks], acc[mt][nt], 0, 0, 0);
    __builtin_amdgcn_s_setprio(0);
    asm volatile("s_waitcnt lgkmcnt(0)" ::: "memory");
    __builtin_amdgcn_s_barrier();
    if (tt + 2 < NT) stage((tt + 2) << 6, c);
  }

  const int rbase = bm * 128 + wm * 64;
  const int cbase = bn * 256 + wn * 64;
  float* outP = outF;
  if constexpr (EPI == 4) outP = outF + (size_t)blockIdx.y * SEQ * N;
#pragma unroll
  for (int mt = 0; mt < 4; ++mt) {
#pragma unroll
    for (int nt = 0; nt < 4; ++nt) {
      const int col = cbase + nt * 16 + lr;
      float bv = 0.f;
      if constexpr (EPI == 1 || EPI == 2) bv = bias[col];
#pragma unroll
      for (int r = 0; r < 4; ++r) {
        const int row = rbase + mt * 16 + lg * 4 + r;
        float v = acc[mt][nt][r] + bv;
        if constexpr (EPI == 2) v = 0.5f * v * (1.f + erff(v * 0.70710678118f));
        if constexpr (EPI == 0 || EPI == 2) outB[(size_t)row * N + col] = f2bf(v);
        else                                outP[(size_t)row * N + col] = v;
      }
    }
  }
}

// ---- GEMM v3: m201-faithful 8-phase 256x256x64, quarter-tile staging ----
// Per phase: {ds_reads; 2x gload16 stage; [vmcnt(6) at ph4 only]; barrier;
// lgkmcnt(0); setprio; 16 MFMA; setprio; barrier}.
// Quadrants (mh,nh): ph1(0,0) ph2(0,1) ph3(1,0) ph4(1,1).
// Reads: ph1 A-mh0(8)+B-nh0(4); ph2 B-nh1(4); ph3 A-mh1(8); ph4 none.
// Stages (quarter=64 rows, 1 gload16 each): ph1 Bq2,q3(t+1); ph2 Aq0,q2(t+2);
// ph3 Bq0,q1(t+2); ph4 Aq1,q3(t+2). vmcnt(6) at ph4 certifies ALL of t+1.
// Each staged region is read-complete (barrier-separated) at issue.
template<int EPI>
__global__ __launch_bounds__(512, 1)
void k_gemm3(const unsigned short* __restrict__ A, const unsigned short* __restrict__ Bt,
             float* __restrict__ outF, unsigned short* __restrict__ outB,
             const float* __restrict__ bias, int N, int K, int gm) {
  __shared__ __align__(16) unsigned short L[65536];
  const int nwg = gridDim.x, pid = blockIdx.x;
  const int qq = nwg >> 3, rr = nwg & 7;
  const int xcd = pid & 7, lo = pid >> 3;
  const int wg = ((xcd < rr) ? xcd * (qq + 1) : rr * (qq + 1) + (xcd - rr) * qq) + lo;
  const int bm = wg % gm, bn = wg / gm;
  const int t = threadIdx.x, lane = t & 63, w = t >> 6;
  const int wm = w >> 2, wn = w & 3, lr = lane & 15, lg = lane >> 4;
  const int NT = K >> 6;

  const unsigned short* gA = A  + (size_t)(bm * 256) * K;
  const unsigned short* gB = Bt + (size_t)(bn * 256) * K;
  const int rowLow = t >> 3;
  const int colOff = ((t & 7) ^ ((t >> 3) & 7)) << 3;
  const unsigned short* pA = gA + (size_t)rowLow * K + colOff;
  const unsigned short* pB = gB + (size_t)rowLow * K + colOff;
  unsigned short* const ldst = L + t * 8;

  auto stageQ = [&](int which, int s, int q) {
    const int ss = (s < NT) ? s : (NT - 1);
    const unsigned short* g = (which ? pB : pA) + (size_t)(q * 64) * K + (ss << 6);
    gload16(g, ldst + ((s & 1) << 15) + (which << 14) + (q << 12));
  };

  int offA[2][4][2], offB[2][2][2];
#pragma unroll
  for (int mh = 0; mh < 2; ++mh)
#pragma unroll
    for (int mt = 0; mt < 4; ++mt)
#pragma unroll
      for (int ks = 0; ks < 2; ++ks) {
        const int row = wm * 128 + mh * 64 + mt * 16 + lr;
        offA[mh][mt][ks] = row * 64 + (((ks * 4 + lg) ^ (row & 7)) << 3);
      }
#pragma unroll
  for (int nh = 0; nh < 2; ++nh)
#pragma unroll
    for (int n2 = 0; n2 < 2; ++n2)
#pragma unroll
      for (int ks = 0; ks < 2; ++ks) {
        const int row = wn * 64 + nh * 32 + n2 * 16 + lr;
        offB[nh][n2][ks] = 16384 + row * 64 + (((ks * 4 + lg) ^ (row & 7)) << 3);
      }

  f32x4 acc[8][4];
#pragma unroll
  for (int i = 0; i < 8; ++i)
#pragma unroll
    for (int j = 0; j < 4; ++j) acc[i][j] = (f32x4){0.f, 0.f, 0.f, 0.f};
  bf16x8 afA[4][2], bf[2][2][2];

  // prologue: tile0 all 8 quarters (oldest), then 6 quarters of tile1
  stageQ(0, 0, 0); stageQ(0, 0, 1); stageQ(0, 0, 2); stageQ(0, 0, 3);
  stageQ(1, 0, 0); stageQ(1, 0, 1); stageQ(1, 0, 2); stageQ(1, 0, 3);
  stageQ(0, 1, 0); stageQ(0, 1, 2); stageQ(1, 1, 0); stageQ(1, 1, 1);
  stageQ(0, 1, 1); stageQ(0, 1, 3);
  asm volatile("s_waitcnt vmcnt(6)" ::: "memory");
  __builtin_amdgcn_s_barrier();

#define PH(BUFO, MH, NHq, RDA, RDB, SW, SS, Q1, Q2, VM) do {                    \
  if (RDA) {                                                                    \
    _Pragma("unroll") for (int mt = 0; mt < 4; ++mt)                            \
    _Pragma("unroll") for (int ks = 0; ks < 2; ++ks)                            \
      afA[mt][ks] = ld_frag(L + (BUFO) + offA[MH][mt][ks]);                     \
  }                                                                             \
  if (RDB) {                                                                    \
    _Pragma("unroll") for (int n2 = 0; n2 < 2; ++n2)                            \
    _Pragma("unroll") for (int ks = 0; ks < 2; ++ks)                            \
      bf[NHq][n2][ks] = ld_frag(L + (BUFO) + offB[NHq][n2][ks]);                \
  }                                                                             \
  stageQ(SW, SS, Q1); stageQ(SW, SS, Q2);                                       \
  if (VM) asm volatile("s_waitcnt vmcnt(6)" ::: "memory");                      \
  __builtin_amdgcn_s_barrier();                                                 \
  asm volatile("s_waitcnt lgkmcnt(0)" ::: "memory");                            \
  __builtin_amdgcn_sched_barrier(0);                                            \
  __builtin_amdgcn_s_setprio(1);                                                \
  _Pragma("unroll") for (int mt = 0; mt < 4; ++mt)                              \
  _Pragma("unroll") for (int n2 = 0; n2 < 2; ++n2)                              \
  _Pragma("unroll") for (int ks = 0; ks < 2; ++ks)                              \
    acc[(MH) * 4 + mt][(NHq) * 2 + n2] = __builtin_amdgcn_mfma_f32_16x16x32_bf16(\
        afA[mt][ks], bf[NHq][n2][ks], acc[(MH) * 4 + mt][(NHq) * 2 + n2], 0, 0, 0);\
  __builtin_amdgcn_s_setprio(0);                                                \
  __builtin_amdgcn_s_barrier();                                                 \
} while (0)

  for (int i = 0; i < (NT >> 1); ++i) {
    const int T0 = 2 * i, T1 = 2 * i + 1;
    PH(0,     0, 0, 1, 1, 1, T0 + 1, 2, 3, 0);
    PH(0,     0, 1, 0, 1, 0, T0 + 2, 0, 2, 0);
    PH(0,     1, 0, 1, 0, 1, T0 + 2, 0, 1, 0);
    PH(0,     1, 1, 0, 0, 0, T0 + 2, 1, 3, 1);
    PH(32768, 0, 0, 1, 1, 1, T1 + 1, 2, 3, 0);
    PH(32768, 0, 1, 0, 1, 0, T1 + 2, 0, 2, 0);
    PH(32768, 1, 0, 1, 0, 1, T1 + 2, 0, 1, 0);
    PH(32768, 1, 1, 0, 0, 0, T1 + 2, 1, 3, 1);
  }
#undef PH

#pragma unroll
  for (int ai = 0; ai < 8; ++ai) {
    const int row0 = bm * 256 + wm * 128 + (ai >> 2) * 64 + (ai & 3) * 16 + lg * 4;
#pragma unroll
    for (int bj = 0; bj < 4; ++bj) {
      const int col = bn * 256 + wn * 64 + (bj >> 1) * 32 + (bj & 1) * 16 + lr;
      float bv = 0.f;
      if constexpr (EPI == 1 || EPI == 2) bv = bias[col];
#pragma unroll
      for (int r = 0; r < 4; ++r) {
        float v = acc[ai][bj][r] + bv;
        if constexpr (EPI == 2) v = 0.5f * v * (1.f + erff(v * 0.70710678118f));
        if constexpr (EPI == 0 || EPI == 2) outB[(size_t)(row0 + r) * N + col] = f2bf(v);
        else                                outF[(size_t)(row0 + r) * N + col] = v;
      }
    }
  }
}

// ---- fused causal ReLA attention, balanced q-strip pairs ----
__global__ __launch_bounds__(256)
void k_rela_attn(const unsigned short* __restrict__ qkv,
                 const unsigned short* __restrict__ vT,
                 unsigned short* __restrict__ obf) {
  const int jb = blockIdx.x;
  const int hd = blockIdx.y;
  const int qbA = jb, qbB = 31 - jb;
  const int t = threadIdx.x, lane = t & 63, w = t >> 6;
  const int lr = lane & 15, lg = lane >> 4;

  __shared__ __align__(16) unsigned short Qs[128 * 64];
  __shared__ __align__(16) unsigned short Ks[64 * 64];
  __shared__ __align__(16) unsigned short Vs[64 * 64];
  __shared__ __align__(16) unsigned short Ps[4][16 * 72];

  const int sr8 = lane >> 3;
  const int sch = ((lane & 7) ^ sr8) << 3;

#pragma unroll
  for (int qi = 0; qi < 4; ++qi) {
    const int i = w * 4 + qi;
    const int rl = i * 8 + sr8;
    const int grow = (rl < 64) ? (qbA * 64 + rl) : (qbB * 64 + rl - 64);
    gload16(qkv + (size_t)grow * (3 * DM) + hd * DHD + sch, Qs + i * 512);
  }
  __syncthreads();

  bf16x8 qfA[2], qfB[2];
#pragma unroll
  for (int ks = 0; ks < 2; ++ks) {
    const int rowA = w * 16 + lr;
    qfA[ks] = ld_frag(&Qs[rowA * 64 + (((ks * 4 + lg) ^ (lr & 7)) << 3)]);
    const int rowB = 64 + w * 16 + lr;
    qfB[ks] = ld_frag(&Qs[rowB * 64 + (((ks * 4 + lg) ^ (lr & 7)) << 3)]);
  }

  const f32x4 zero = {0.f, 0.f, 0.f, 0.f};
  f32x4 accA[4], accB[4];
#pragma unroll
  for (int nt = 0; nt < 4; ++nt) { accA[nt] = zero; accB[nt] = zero; }

  auto tile_step = [&](const bf16x8* qf, f32x4* acc, int qb, int kt) {
    f32x4 sv[4];
#pragma unroll
    for (int nt = 0; nt < 4; ++nt) sv[nt] = zero;
#pragma unroll
    for (int ks = 0; ks < 2; ++ks)
#pragma unroll
      for (int nt = 0; nt < 4; ++nt) {
        bf16x8 kf = ld_frag(&Ks[(nt * 16 + lr) * 64 + (((ks * 4 + lg) ^ (lr & 7)) << 3)]);
        sv[nt] = __builtin_amdgcn_mfma_f32_16x16x32_bf16(qf[ks], kf, sv[nt], 0, 0, 0);
      }
    const bool diag = (kt == qb);
#pragma unroll
    for (int nt = 0; nt < 4; ++nt)
#pragma unroll
      for (int r = 0; r < 4; ++r) {
        float v = fmaxf(sv[nt][r], 0.f) * 0.125f;
        if (diag) {
          const int ii = w * 16 + lg * 4 + r;
          const int jj = nt * 16 + lr;
          if (jj > ii) v = 0.f;
        }
        Ps[w][(lg * 4 + r) * 72 + nt * 16 + lr] = f2bf(v);
      }
#pragma unroll
    for (int ks = 0; ks < 2; ++ks) {
      bf16x8 pf = ld_frag(&Ps[w][lr * 72 + ks * 32 + lg * 8]);
#pragma unroll
      for (int nt = 0; nt < 4; ++nt) {
        bf16x8 vf = ld_frag(&Vs[(nt * 16 + lr) * 64 + (((ks * 4 + lg) ^ (lr & 7)) << 3)]);
        acc[nt] = __builtin_amdgcn_mfma_f32_16x16x32_bf16(pf, vf, acc[nt], 0, 0, 0);
      }
    }
  };

  for (int kt = 0; kt <= qbB; ++kt) {
    __syncthreads();
#pragma unroll
    for (int qi = 0; qi < 2; ++qi) {
      const int i = w * 2 + qi;
      const int rl = i * 8 + sr8;
      gload16(qkv + (size_t)(kt * 64 + rl) * (3 * DM) + DM + hd * DHD + sch, Ks + i * 512);
      gload16(vT + (size_t)(hd * DHD + rl) * SEQ + kt * 64 + sch, Vs + i * 512);
    }
    __syncthreads();
    tile_step(qfB, accB, qbB, kt);
    if (kt <= qbA) tile_step(qfA, accA, qbA, kt);
  }

#pragma unroll
  for (int nt = 0; nt < 4; ++nt)
#pragma unroll
    for (int r = 0; r < 4; ++r) {
      const int col = hd * DHD + nt * 16 + lr;
      const int rowA = qbA * 64 + w * 16 + lg * 4 + r;
      obf[(size_t)rowA * DM + col] = f2bf(accA[nt][r]);
      const int rowB = qbB * 64 + w * 16 + lg * 4 + r;
      obf[(size_t)rowB * DM + col] = f2bf(accB[nt][r]);
    }
}

extern "C" void kernel_launch(void* const* d_in, const int* in_sizes, int n_in,
                              void* d_out, int out_size, void* d_ws, size_t ws_size,
                              hipStream_t stream) {
  const int*   x       = (const int*)d_in[0];
  const float* tok_emb = (const float*)d_in[1];
  const float* pos_emb = (const float*)d_in[2];
  const float* attn_ng = (const float*)d_in[3];
  const float* attn_nb = (const float*)d_in[4];
  const float* wqkv    = (const float*)d_in[5];
  const float* wo      = (const float*)d_in[6];
  const float* bo      = (const float*)d_in[7];
  const float* out_ng  = (const float*)d_in[8];
  const float* out_nb  = (const float*)d_in[9];
  const float* ff_ng   = (const float*)d_in[10];
  const float* ff_nb   = (const float*)d_in[11];
  const float* w1      = (const float*)d_in[12];
  const float* b1      = (const float*)d_in[13];
  const float* w2      = (const float*)d_in[14];
  const float* b2      = (const float*)d_in[15];
  const float* fin_g   = (const float*)d_in[16];
  const float* fin_b   = (const float*)d_in[17];
  const float* w_logit = (const float*)d_in[18];
  const float* b_logit = (const float*)d_in[19];
  float* out = (float*)d_out;

  char* ws = (char*)d_ws;
  size_t off = 0;
  auto alloc = [&](size_t bytes) -> void* {
    void* p = ws + off;
    off = (off + bytes + 255) & ~(size_t)255;
    return p;
  };
  unsigned short* wqkvT = (unsigned short*)alloc(4ull * 3072 * 1024 * 2);
  unsigned short* woT   = (unsigned short*)alloc(4ull * 1024 * 1024 * 2);
  unsigned short* w1T   = (unsigned short*)alloc(4ull * 4096 * 1024 * 2);
  unsigned short* w2T   = (unsigned short*)alloc(4ull * 1024 * 4096 * 2);
  unsigned short* wlogT = (unsigned short*)alloc((size_t)NV * 1024 * 2);
  float*          h     = (float*)alloc((size_t)SEQ * DM * 4);
  unsigned short* ybf   = (unsigned short*)alloc((size_t)SEQ * DM * 2);
  unsigned short* qkvbf = (unsigned short*)alloc((size_t)SEQ * 3 * DM * 2);
  unsigned short* vTb   = (unsigned short*)alloc((size_t)DM * SEQ * 2);
  unsigned short* obf   = (unsigned short*)alloc((size_t)SEQ * DM * 2);
  float*          tmpf  = (float*)alloc((size_t)SEQ * DM * 4);
  unsigned short* ffbf  = (unsigned short*)alloc((size_t)SEQ * FFD * 2);
  float*          slabs = (float*)alloc(4ull * SEQ * DM * 4);
  (void)ws_size; (void)in_sizes; (void)n_in; (void)out_size;

  const dim3 B(256);
  const dim3 G2(512);

  k_transpose_bf16<<<dim3(16, 48, 4), B, 0, stream>>>(wqkv, wqkvT, 1024, 3072, (size_t)1024 * 3072);
  k_transpose_bf16<<<dim3(16, 16, 4), B, 0, stream>>>(wo, woT, 1024, 1024, (size_t)1024 * 1024);
  k_transpose_bf16<<<dim3(16, 64, 4), B, 0, stream>>>(w1, w1T, 1024, 4096, (size_t)1024 * 4096);
  k_transpose_bf16<<<dim3(64, 16, 4), B, 0, stream>>>(w2, w2T, 4096, 1024, (size_t)4096 * 1024);
  k_transpose_bf16<<<dim3(16, 500, 1), B, 0, stream>>>(w_logit, wlogT, 1024, NV, 0);

  k_embed<<<SEQ, B, 0, stream>>>(x, tok_emb, pos_emb, h);

  for (int l = 0; l < 4; ++l) {
    k_ln_bf16<<<SEQ, B, 0, stream>>>(h, attn_ng + l * DM, attn_nb + l * DM, ybf);
    k_gemm2<0><<<dim3(192), G2, 0, stream>>>(
        ybf, wqkvT + (size_t)l * 3072 * 1024, nullptr, qkvbf, nullptr, 3072, 1024, 1024, 16);
    k_vT<<<dim3(SEQ / 32, DM / 32), B, 0, stream>>>(qkvbf, vTb);
    k_rela_attn<<<dim3(16, NH), B, 0, stream>>>(qkvbf, vTb, obf);
    k_gemm2<1><<<dim3(64), G2, 0, stream>>>(
        obf, woT + (size_t)l * 1024 * 1024, tmpf, nullptr, bo + l * DM, 1024, 1024, 1024, 16);
    k_add_ln_ln<<<SEQ, B, 0, stream>>>(h, tmpf, out_ng + l * DM, out_nb + l * DM,
                                       ff_ng + l * DM, ff_nb + l * DM, ybf);
    k_gemm2<2><<<dim3(256), G2, 0, stream>>>(
        ybf, w1T + (size_t)l * 4096 * 1024, nullptr, ffbf, b1 + l * FFD, 4096, 1024, 1024, 16);
    k_gemm2<4><<<dim3(64, 4), G2, 0, stream>>>(
        ffbf, w2T + (size_t)l * 1024 * 4096, slabs, nullptr, nullptr, 1024, 4096, 1024, 16);
    k_red_add<<<SEQ, B, 0, stream>>>(h, slabs, b2 + l * DM);
  }

  k_ln_bf16<<<SEQ, B, 0, stream>>>(h, fin_g, fin_b, ybf);
  k_gemm3<1><<<dim3(1000), G2, 0, stream>>>(ybf, wlogT, out, nullptr, b_logit, NV, 1024, 8);
}

// Round 6
// 1050.476 us; speedup vs baseline: 1.4806x; 1.0348x over previous
//
#include <hip/hip_runtime.h>
#include <hip/hip_bf16.h>
#include <math.h>

#define SEQ   2048
#define DM    1024
#define NH    16
#define DHD   64
#define FFD   4096
#define NV    32000

typedef __bf16 bf16x8 __attribute__((ext_vector_type(8)));
typedef float  f32x4  __attribute__((ext_vector_type(4)));

typedef __attribute__((address_space(1))) void* gas_ptr;
typedef __attribute__((address_space(3))) void* las_ptr;

static __device__ __forceinline__ void gload16(const void* g, void* l) {
  __builtin_amdgcn_global_load_lds((gas_ptr)g, (las_ptr)l, 16, 0, 0);
}

static __device__ __forceinline__ unsigned short f2bf(float f) {
  unsigned int x = __float_as_uint(f);
  return (unsigned short)((x + 0x7fffu + ((x >> 16) & 1u)) >> 16);
}

static __device__ __forceinline__ bf16x8 ld_frag(const unsigned short* p) {
  union { uint4 u; bf16x8 v; } r;
  r.u = *(const uint4*)p;
  return r.v;
}

// ---- transpose + f32->bf16 convert, batched over blockIdx.z layers ----
__global__ __launch_bounds__(256)
void k_transpose_bf16(const float* __restrict__ in, unsigned short* __restrict__ out,
                      int K, int N, size_t lstride) {
  in  += (size_t)blockIdx.z * lstride;
  out += (size_t)blockIdx.z * lstride;
  __shared__ float tl[64 * 65];
  const int bk = blockIdx.x * 64, bn = blockIdx.y * 64;
  const int t = threadIdx.x;
  const int tx = t & 15, ty = t >> 4;
#pragma unroll
  for (int i = 0; i < 4; ++i) {
    const int r = i * 16 + ty;
    float4 v = *(const float4*)&in[(size_t)(bk + r) * N + bn + tx * 4];
    tl[(tx * 4 + 0) * 65 + r] = v.x;
    tl[(tx * 4 + 1) * 65 + r] = v.y;
    tl[(tx * 4 + 2) * 65 + r] = v.z;
    tl[(tx * 4 + 3) * 65 + r] = v.w;
  }
  __syncthreads();
#pragma unroll
  for (int j = 0; j < 2; ++j) {
    const int f = j * 256 + t;
    const int n = f >> 3, kc = (f & 7) * 8;
    union { unsigned short u[8]; uint4 v; } pk;
#pragma unroll
    for (int e = 0; e < 8; ++e) pk.u[e] = f2bf(tl[n * 65 + kc + e]);
    *(uint4*)&out[(size_t)(bn + n) * K + bk + kc] = pk.v;
  }
}

// ---- per-head V transpose ----
__global__ __launch_bounds__(256)
void k_vT(const unsigned short* __restrict__ qkv, unsigned short* __restrict__ vT) {
  __shared__ unsigned short tile[32][33];
  const int bs = blockIdx.x * 32, bd = blockIdx.y * 32;
  const int tx = threadIdx.x & 31, ty = threadIdx.x >> 5;
#pragma unroll
  for (int r = ty; r < 32; r += 8)
    tile[r][tx] = qkv[(size_t)(bs + r) * (3 * DM) + 2 * DM + bd + tx];
  __syncthreads();
#pragma unroll
  for (int r = ty; r < 32; r += 8)
    vT[(size_t)(bd + r) * SEQ + bs + tx] = tile[tx][r];
}

// ---- embedding ----
__global__ __launch_bounds__(256)
void k_embed(const int* __restrict__ x, const float* __restrict__ tok,
             const float* __restrict__ pos, float* __restrict__ h) {
  const int row = blockIdx.x;
  const int d = threadIdx.x * 4;
  const int tk = x[row];
  float4 a = *(const float4*)(tok + (size_t)tk * DM + d);
  float4 p = *(const float4*)(pos + (size_t)row * DM + d);
  float4 o; o.x = a.x + p.x; o.y = a.y + p.y; o.z = a.z + p.z; o.w = a.w + p.w;
  *(float4*)(h + (size_t)row * DM + d) = o;
}

// ---- LayerNorm(in) -> bf16 out ----
__global__ __launch_bounds__(256)
void k_ln_bf16(const float* __restrict__ in, const float* __restrict__ g,
               const float* __restrict__ b, unsigned short* __restrict__ out) {
  const int row = blockIdx.x, t = threadIdx.x;
  float4 v = *(const float4*)(in + (size_t)row * DM + t * 4);
  float s = v.x + v.y + v.z + v.w;
  float q = v.x * v.x + v.y * v.y + v.z * v.z + v.w * v.w;
#pragma unroll
  for (int o = 32; o; o >>= 1) { s += __shfl_xor(s, o); q += __shfl_xor(q, o); }
  __shared__ float ls[4], lq[4];
  if ((t & 63) == 0) { ls[t >> 6] = s; lq[t >> 6] = q; }
  __syncthreads();
  s = ls[0] + ls[1] + ls[2] + ls[3];
  q = lq[0] + lq[1] + lq[2] + lq[3];
  const float mean = s * (1.f / DM);
  const float rstd = rsqrtf(q * (1.f / DM) - mean * mean + 1e-5f);
  float4 gg = *(const float4*)(g + t * 4);
  float4 bb = *(const float4*)(b + t * 4);
  ushort4 o4;
  o4.x = f2bf((v.x - mean) * rstd * gg.x + bb.x);
  o4.y = f2bf((v.y - mean) * rstd * gg.y + bb.y);
  o4.z = f2bf((v.z - mean) * rstd * gg.z + bb.z);
  o4.w = f2bf((v.w - mean) * rstd * gg.w + bb.w);
  *(ushort4*)(out + (size_t)row * DM + t * 4) = o4;
}

// ---- h += LN1(bo + sum4 slabs); out = bf16(LN2(h)) ----
__global__ __launch_bounds__(256)
void k_addslab_ln_ln(float* __restrict__ h, const float* __restrict__ sl,
                     const float* __restrict__ bo,
                     const float* __restrict__ g1, const float* __restrict__ b1,
                     const float* __restrict__ g2, const float* __restrict__ b2,
                     unsigned short* __restrict__ out) {
  const int row = blockIdx.x, t = threadIdx.x;
  __shared__ float ls[4], lq[4], ls2[4], lq2[4];
  const size_t idx = (size_t)row * DM + t * 4;
  float4 v = *(const float4*)(bo + t * 4);
#pragma unroll
  for (int c = 0; c < 4; ++c) {
    float4 p = *(const float4*)(sl + (size_t)c * SEQ * DM + idx);
    v.x += p.x; v.y += p.y; v.z += p.z; v.w += p.w;
  }
  float s = v.x + v.y + v.z + v.w;
  float q = v.x * v.x + v.y * v.y + v.z * v.z + v.w * v.w;
#pragma unroll
  for (int o = 32; o; o >>= 1) { s += __shfl_xor(s, o); q += __shfl_xor(q, o); }
  if ((t & 63) == 0) { ls[t >> 6] = s; lq[t >> 6] = q; }
  __syncthreads();
  s = ls[0] + ls[1] + ls[2] + ls[3];
  q = lq[0] + lq[1] + lq[2] + lq[3];
  const float mean = s * (1.f / DM);
  const float rstd = rsqrtf(q * (1.f / DM) - mean * mean + 1e-5f);
  float4 gg = *(const float4*)(g1 + t * 4);
  float4 bb = *(const float4*)(b1 + t * 4);
  float4 hv = *(const float4*)(h + idx);
  hv.x += (v.x - mean) * rstd * gg.x + bb.x;
  hv.y += (v.y - mean) * rstd * gg.y + bb.y;
  hv.z += (v.z - mean) * rstd * gg.z + bb.z;
  hv.w += (v.w - mean) * rstd * gg.w + bb.w;
  *(float4*)(h + idx) = hv;
  float s2 = hv.x + hv.y + hv.z + hv.w;
  float q2 = hv.x * hv.x + hv.y * hv.y + hv.z * hv.z + hv.w * hv.w;
#pragma unroll
  for (int o = 32; o; o >>= 1) { s2 += __shfl_xor(s2, o); q2 += __shfl_xor(q2, o); }
  if ((t & 63) == 0) { ls2[t >> 6] = s2; lq2[t >> 6] = q2; }
  __syncthreads();
  s2 = ls2[0] + ls2[1] + ls2[2] + ls2[3];
  q2 = lq2[0] + lq2[1] + lq2[2] + lq2[3];
  const float mean2 = s2 * (1.f / DM);
  const float rstd2 = rsqrtf(q2 * (1.f / DM) - mean2 * mean2 + 1e-5f);
  float4 g2v = *(const float4*)(g2 + t * 4);
  float4 b2v = *(const float4*)(b2 + t * 4);
  ushort4 o4;
  o4.x = f2bf((hv.x - mean2) * rstd2 * g2v.x + b2v.x);
  o4.y = f2bf((hv.y - mean2) * rstd2 * g2v.y + b2v.y);
  o4.z = f2bf((hv.z - mean2) * rstd2 * g2v.z + b2v.z);
  o4.w = f2bf((hv.w - mean2) * rstd2 * g2v.w + b2v.w);
  *(ushort4*)(out + (size_t)row * DM + t * 4) = o4;
}

// ---- h += b2 + sum of 4 split-K slabs ----
__global__ __launch_bounds__(256)
void k_red_add(float* __restrict__ h, const float* __restrict__ sl,
               const float* __restrict__ b2) {
  const int row = blockIdx.x, d = threadIdx.x * 4;
  const size_t idx = (size_t)row * DM + d;
  float4 hv = *(const float4*)(h + idx);
  float4 bb = *(const float4*)(b2 + d);
  hv.x += bb.x; hv.y += bb.y; hv.z += bb.z; hv.w += bb.w;
#pragma unroll
  for (int c = 0; c < 4; ++c) {
    float4 p = *(const float4*)(sl + (size_t)c * SEQ * DM + idx);
    hv.x += p.x; hv.y += p.y; hv.z += p.z; hv.w += p.w;
  }
  *(float4*)(h + idx) = hv;
}

// ---- GEMM v2 (2-phase 128x256), kLen slab via blockIdx.y ----
// EPI: 0 bf16; 1 +bias f32; 2 +bias gelu bf16; 4 slab f32 partial (no bias)
template<int EPI>
__global__ __launch_bounds__(512, 1)
void k_gemm2(const unsigned short* __restrict__ A, const unsigned short* __restrict__ Bt,
             float* __restrict__ outF, unsigned short* __restrict__ outB,
             const float* __restrict__ bias, int N, int K, int kLen, int gm) {
  __shared__ __align__(16) unsigned short L[49152];
  const int nwg = gridDim.x, pid = blockIdx.x;
  const int qq = nwg >> 3, rr = nwg & 7;
  const int xcd = pid & 7, lo = pid >> 3;
  const int wg = ((xcd < rr) ? xcd * (qq + 1) : rr * (qq + 1) + (xcd - rr) * qq) + lo;
  const int bm = wg % gm, bn = wg / gm;
  const int kOff = blockIdx.y * kLen;
  const int t = threadIdx.x, lane = t & 63, w = t >> 6;
  const int wm = w >> 2, wn = w & 3, lr = lane & 15, lg = lane >> 4;

  const unsigned short* gA[2]; unsigned short* lA[2];
  const unsigned short* gB[4]; unsigned short* lB[4];
#pragma unroll
  for (int j = 0; j < 2; ++j) {
    const int f = j * 512 + t, row = f >> 3, c = f & 7;
    gA[j] = A + (size_t)(bm * 128 + row) * K + kOff + ((c ^ (row & 7)) << 3);
    lA[j] = L + f * 8;
  }
#pragma unroll
  for (int j = 0; j < 4; ++j) {
    const int f = j * 512 + t, row = f >> 3, c = f & 7;
    gB[j] = Bt + (size_t)(bn * 256 + row) * K + kOff + ((c ^ (row & 7)) << 3);
    lB[j] = L + 16384 + f * 8;
  }
  auto stage = [&](int k0, int c) {
#pragma unroll
    for (int j = 0; j < 2; ++j) gload16(gA[j] + k0, lA[j] + c * 8192);
#pragma unroll
    for (int j = 0; j < 4; ++j) gload16(gB[j] + k0, lB[j] + c * 16384);
  };

  int offA[4][2], offB[4][2];
#pragma unroll
  for (int mt = 0; mt < 4; ++mt)
#pragma unroll
    for (int ks = 0; ks < 2; ++ks) {
      const int rowA = wm * 64 + mt * 16 + lr;
      offA[mt][ks] = rowA * 64 + (((ks * 4 + lg) ^ (rowA & 7)) << 3);
      const int rowB = wn * 64 + mt * 16 + lr;
      offB[mt][ks] = rowB * 64 + (((ks * 4 + lg) ^ (rowB & 7)) << 3);
    }

  const f32x4 zero = {0.f, 0.f, 0.f, 0.f};
  f32x4 acc[4][4];
#pragma unroll
  for (int i = 0; i < 4; ++i)
#pragma unroll
    for (int j = 0; j < 4; ++j) acc[i][j] = zero;

  const int NT = kLen >> 6;
  stage(0, 0);
  if (NT > 1) stage(64, 1);

  for (int tt = 0; tt < NT; ++tt) {
    const int c = tt & 1;
    if (tt + 1 < NT) asm volatile("s_waitcnt vmcnt(6)" ::: "memory");
    else             asm volatile("s_waitcnt vmcnt(0)" ::: "memory");
    __builtin_amdgcn_s_barrier();
    const unsigned short* Ab = L + c * 8192;
    const unsigned short* Bb = L + 16384 + c * 16384;
    bf16x8 af[4][2], bfr[4][2];
#pragma unroll
    for (int mt = 0; mt < 4; ++mt)
#pragma unroll
      for (int ks = 0; ks < 2; ++ks) {
        af[mt][ks]  = ld_frag(Ab + offA[mt][ks]);
        bfr[mt][ks] = ld_frag(Bb + offB[mt][ks]);
      }
    __builtin_amdgcn_s_setprio(1);
#pragma unroll
    for (int mt = 0; mt < 4; ++mt)
#pragma unroll
      for (int nt = 0; nt < 4; ++nt)
#pragma unroll
        for (int ks = 0; ks < 2; ++ks)
          acc[mt][nt] = __builtin_amdgcn_mfma_f32_16x16x32_bf16(af[mt][ks], bfr[nt][ks], acc[mt][nt], 0, 0, 0);
    __builtin_amdgcn_s_setprio(0);
    __builtin_amdgcn_s_barrier();
    if (tt + 2 < NT) stage((tt + 2) << 6, c);
  }

  const int rbase = bm * 128 + wm * 64;
  const int cbase = bn * 256 + wn * 64;
  float* outP = outF;
  if constexpr (EPI == 4) outP = outF + (size_t)blockIdx.y * SEQ * N;
#pragma unroll
  for (int mt = 0; mt < 4; ++mt) {
#pragma unroll
    for (int nt = 0; nt < 4; ++nt) {
      const int col = cbase + nt * 16 + lr;
      float bv = 0.f;
      if constexpr (EPI == 1 || EPI == 2) bv = bias[col];
#pragma unroll
      for (int r = 0; r < 4; ++r) {
        const int row = rbase + mt * 16 + lg * 4 + r;
        float v = acc[mt][nt][r] + bv;
        if constexpr (EPI == 2) v = 0.5f * v * (1.f + erff(v * 0.70710678118f));
        if constexpr (EPI == 0 || EPI == 2) outB[(size_t)row * N + col] = f2bf(v);
        else                                outP[(size_t)row * N + col] = v;
      }
    }
  }
}

// ---- GEMM v3: 8-phase 256x256x64, quarter-tile staging, compiler lgkm ----
// Per phase: {ds_reads; 2x gload16 stage; [vmcnt(6) at ph4/8 only]; barrier;
// setprio; 16 MFMA (compiler inserts fine-grained lgkmcnt); setprio; barrier}.
// NOTE: no explicit lgkmcnt(0)/sched_barrier — ld_frag is a compiler load, so
// dependency-driven lgkm waits let MFMA 0 start before reads 2..7 land (r5's
// forced drain serialized this and capped MfmaUtil at 25%).
template<int EPI>
__global__ __launch_bounds__(512, 1)
void k_gemm3(const unsigned short* __restrict__ A, const unsigned short* __restrict__ Bt,
             float* __restrict__ outF, unsigned short* __restrict__ outB,
             const float* __restrict__ bias, int N, int K, int gm) {
  __shared__ __align__(16) unsigned short L[65536];
  const int nwg = gridDim.x, pid = blockIdx.x;
  const int qq = nwg >> 3, rr = nwg & 7;
  const int xcd = pid & 7, lo = pid >> 3;
  const int wg = ((xcd < rr) ? xcd * (qq + 1) : rr * (qq + 1) + (xcd - rr) * qq) + lo;
  const int bm = wg % gm, bn = wg / gm;
  const int t = threadIdx.x, lane = t & 63, w = t >> 6;
  const int wm = w >> 2, wn = w & 3, lr = lane & 15, lg = lane >> 4;
  const int NT = K >> 6;

  const unsigned short* gA = A  + (size_t)(bm * 256) * K;
  const unsigned short* gB = Bt + (size_t)(bn * 256) * K;
  const int rowLow = t >> 3;
  const int colOff = ((t & 7) ^ ((t >> 3) & 7)) << 3;
  const unsigned short* pA = gA + (size_t)rowLow * K + colOff;
  const unsigned short* pB = gB + (size_t)rowLow * K + colOff;
  unsigned short* const ldst = L + t * 8;

  auto stageQ = [&](int which, int s, int q) {
    const int ss = (s < NT) ? s : (NT - 1);
    const unsigned short* g = (which ? pB : pA) + (size_t)(q * 64) * K + (ss << 6);
    gload16(g, ldst + ((s & 1) << 15) + (which << 14) + (q << 12));
  };

  int offA[2][4][2], offB[2][2][2];
#pragma unroll
  for (int mh = 0; mh < 2; ++mh)
#pragma unroll
    for (int mt = 0; mt < 4; ++mt)
#pragma unroll
      for (int ks = 0; ks < 2; ++ks) {
        const int row = wm * 128 + mh * 64 + mt * 16 + lr;
        offA[mh][mt][ks] = row * 64 + (((ks * 4 + lg) ^ (row & 7)) << 3);
      }
#pragma unroll
  for (int nh = 0; nh < 2; ++nh)
#pragma unroll
    for (int n2 = 0; n2 < 2; ++n2)
#pragma unroll
      for (int ks = 0; ks < 2; ++ks) {
        const int row = wn * 64 + nh * 32 + n2 * 16 + lr;
        offB[nh][n2][ks] = 16384 + row * 64 + (((ks * 4 + lg) ^ (row & 7)) << 3);
      }

  f32x4 acc[8][4];
#pragma unroll
  for (int i = 0; i < 8; ++i)
#pragma unroll
    for (int j = 0; j < 4; ++j) acc[i][j] = (f32x4){0.f, 0.f, 0.f, 0.f};
  bf16x8 afA[4][2], bf[2][2][2];

  // prologue: tile0 all 8 quarters (oldest), then 6 quarters of tile1
  stageQ(0, 0, 0); stageQ(0, 0, 1); stageQ(0, 0, 2); stageQ(0, 0, 3);
  stageQ(1, 0, 0); stageQ(1, 0, 1); stageQ(1, 0, 2); stageQ(1, 0, 3);
  stageQ(0, 1, 0); stageQ(0, 1, 2); stageQ(1, 1, 0); stageQ(1, 1, 1);
  stageQ(0, 1, 1); stageQ(0, 1, 3);
  asm volatile("s_waitcnt vmcnt(6)" ::: "memory");
  __builtin_amdgcn_s_barrier();

#define PH(BUFO, MH, NHq, RDA, RDB, SW, SS, Q1, Q2, VM) do {                    \
  if (RDA) {                                                                    \
    _Pragma("unroll") for (int mt = 0; mt < 4; ++mt)                            \
    _Pragma("unroll") for (int ks = 0; ks < 2; ++ks)                            \
      afA[mt][ks] = ld_frag(L + (BUFO) + offA[MH][mt][ks]);                     \
  }                                                                             \
  if (RDB) {                                                                    \
    _Pragma("unroll") for (int n2 = 0; n2 < 2; ++n2)                            \
    _Pragma("unroll") for (int ks = 0; ks < 2; ++ks)                            \
      bf[NHq][n2][ks] = ld_frag(L + (BUFO) + offB[NHq][n2][ks]);                \
  }                                                                             \
  stageQ(SW, SS, Q1); stageQ(SW, SS, Q2);                                       \
  if (VM) asm volatile("s_waitcnt vmcnt(6)" ::: "memory");                      \
  __builtin_amdgcn_s_barrier();                                                 \
  __builtin_amdgcn_s_setprio(1);                                                \
  _Pragma("unroll") for (int mt = 0; mt < 4; ++mt)                              \
  _Pragma("unroll") for (int n2 = 0; n2 < 2; ++n2)                              \
  _Pragma("unroll") for (int ks = 0; ks < 2; ++ks)                              \
    acc[(MH) * 4 + mt][(NHq) * 2 + n2] = __builtin_amdgcn_mfma_f32_16x16x32_bf16(\
        afA[mt][ks], bf[NHq][n2][ks], acc[(MH) * 4 + mt][(NHq) * 2 + n2], 0, 0, 0);\
  __builtin_amdgcn_s_setprio(0);                                                \
  __builtin_amdgcn_s_barrier();                                                 \
} while (0)

  for (int i = 0; i < (NT >> 1); ++i) {
    const int T0 = 2 * i, T1 = 2 * i + 1;
    PH(0,     0, 0, 1, 1, 1, T0 + 1, 2, 3, 0);
    PH(0,     0, 1, 0, 1, 0, T0 + 2, 0, 2, 0);
    PH(0,     1, 0, 1, 0, 1, T0 + 2, 0, 1, 0);
    PH(0,     1, 1, 0, 0, 0, T0 + 2, 1, 3, 1);
    PH(32768, 0, 0, 1, 1, 1, T1 + 1, 2, 3, 0);
    PH(32768, 0, 1, 0, 1, 0, T1 + 2, 0, 2, 0);
    PH(32768, 1, 0, 1, 0, 1, T1 + 2, 0, 1, 0);
    PH(32768, 1, 1, 0, 0, 0, T1 + 2, 1, 3, 1);
  }
#undef PH

#pragma unroll
  for (int ai = 0; ai < 8; ++ai) {
    const int row0 = bm * 256 + wm * 128 + (ai >> 2) * 64 + (ai & 3) * 16 + lg * 4;
#pragma unroll
    for (int bj = 0; bj < 4; ++bj) {
      const int col = bn * 256 + wn * 64 + (bj >> 1) * 32 + (bj & 1) * 16 + lr;
      float bv = 0.f;
      if constexpr (EPI == 1 || EPI == 2) bv = bias[col];
#pragma unroll
      for (int r = 0; r < 4; ++r) {
        float v = acc[ai][bj][r] + bv;
        if constexpr (EPI == 2) v = 0.5f * v * (1.f + erff(v * 0.70710678118f));
        if constexpr (EPI == 0 || EPI == 2) outB[(size_t)(row0 + r) * N + col] = f2bf(v);
        else                                outF[(size_t)(row0 + r) * N + col] = v;
      }
    }
  }
}

// ---- fused causal ReLA attention, balanced q-strip pairs ----
__global__ __launch_bounds__(256)
void k_rela_attn(const unsigned short* __restrict__ qkv,
                 const unsigned short* __restrict__ vT,
                 unsigned short* __restrict__ obf) {
  const int jb = blockIdx.x;
  const int hd = blockIdx.y;
  const int qbA = jb, qbB = 31 - jb;
  const int t = threadIdx.x, lane = t & 63, w = t >> 6;
  const int lr = lane & 15, lg = lane >> 4;

  __shared__ __align__(16) unsigned short Qs[128 * 64];
  __shared__ __align__(16) unsigned short Ks[64 * 64];
  __shared__ __align__(16) unsigned short Vs[64 * 64];
  __shared__ __align__(16) unsigned short Ps[4][16 * 72];

  const int sr8 = lane >> 3;
  const int sch = ((lane & 7) ^ sr8) << 3;

#pragma unroll
  for (int qi = 0; qi < 4; ++qi) {
    const int i = w * 4 + qi;
    const int rl = i * 8 + sr8;
    const int grow = (rl < 64) ? (qbA * 64 + rl) : (qbB * 64 + rl - 64);
    gload16(qkv + (size_t)grow * (3 * DM) + hd * DHD + sch, Qs + i * 512);
  }
  __syncthreads();

  bf16x8 qfA[2], qfB[2];
#pragma unroll
  for (int ks = 0; ks < 2; ++ks) {
    const int rowA = w * 16 + lr;
    qfA[ks] = ld_frag(&Qs[rowA * 64 + (((ks * 4 + lg) ^ (lr & 7)) << 3)]);
    const int rowB = 64 + w * 16 + lr;
    qfB[ks] = ld_frag(&Qs[rowB * 64 + (((ks * 4 + lg) ^ (lr & 7)) << 3)]);
  }

  const f32x4 zero = {0.f, 0.f, 0.f, 0.f};
  f32x4 accA[4], accB[4];
#pragma unroll
  for (int nt = 0; nt < 4; ++nt) { accA[nt] = zero; accB[nt] = zero; }

  auto tile_step = [&](const bf16x8* qf, f32x4* acc, int qb, int kt) {
    f32x4 sv[4];
#pragma unroll
    for (int nt = 0; nt < 4; ++nt) sv[nt] = zero;
#pragma unroll
    for (int ks = 0; ks < 2; ++ks)
#pragma unroll
      for (int nt = 0; nt < 4; ++nt) {
        bf16x8 kf = ld_frag(&Ks[(nt * 16 + lr) * 64 + (((ks * 4 + lg) ^ (lr & 7)) << 3)]);
        sv[nt] = __builtin_amdgcn_mfma_f32_16x16x32_bf16(qf[ks], kf, sv[nt], 0, 0, 0);
      }
    const bool diag = (kt == qb);
#pragma unroll
    for (int nt = 0; nt < 4; ++nt)
#pragma unroll
      for (int r = 0; r < 4; ++r) {
        float v = fmaxf(sv[nt][r], 0.f) * 0.125f;
        if (diag) {
          const int ii = w * 16 + lg * 4 + r;
          const int jj = nt * 16 + lr;
          if (jj > ii) v = 0.f;
        }
        Ps[w][(lg * 4 + r) * 72 + nt * 16 + lr] = f2bf(v);
      }
#pragma unroll
    for (int ks = 0; ks < 2; ++ks) {
      bf16x8 pf = ld_frag(&Ps[w][lr * 72 + ks * 32 + lg * 8]);
#pragma unroll
      for (int nt = 0; nt < 4; ++nt) {
        bf16x8 vf = ld_frag(&Vs[(nt * 16 + lr) * 64 + (((ks * 4 + lg) ^ (lr & 7)) << 3)]);
        acc[nt] = __builtin_amdgcn_mfma_f32_16x16x32_bf16(pf, vf, acc[nt], 0, 0, 0);
      }
    }
  };

  for (int kt = 0; kt <= qbB; ++kt) {
    __syncthreads();
#pragma unroll
    for (int qi = 0; qi < 2; ++qi) {
      const int i = w * 2 + qi;
      const int rl = i * 8 + sr8;
      gload16(qkv + (size_t)(kt * 64 + rl) * (3 * DM) + DM + hd * DHD + sch, Ks + i * 512);
      gload16(vT + (size_t)(hd * DHD + rl) * SEQ + kt * 64 + sch, Vs + i * 512);
    }
    __syncthreads();
    tile_step(qfB, accB, qbB, kt);
    if (kt <= qbA) tile_step(qfA, accA, qbA, kt);
  }

#pragma unroll
  for (int nt = 0; nt < 4; ++nt)
#pragma unroll
    for (int r = 0; r < 4; ++r) {
      const int col = hd * DHD + nt * 16 + lr;
      const int rowA = qbA * 64 + w * 16 + lg * 4 + r;
      obf[(size_t)rowA * DM + col] = f2bf(accA[nt][r]);
      const int rowB = qbB * 64 + w * 16 + lg * 4 + r;
      obf[(size_t)rowB * DM + col] = f2bf(accB[nt][r]);
    }
}

extern "C" void kernel_launch(void* const* d_in, const int* in_sizes, int n_in,
                              void* d_out, int out_size, void* d_ws, size_t ws_size,
                              hipStream_t stream) {
  const int*   x       = (const int*)d_in[0];
  const float* tok_emb = (const float*)d_in[1];
  const float* pos_emb = (const float*)d_in[2];
  const float* attn_ng = (const float*)d_in[3];
  const float* attn_nb = (const float*)d_in[4];
  const float* wqkv    = (const float*)d_in[5];
  const float* wo      = (const float*)d_in[6];
  const float* bo      = (const float*)d_in[7];
  const float* out_ng  = (const float*)d_in[8];
  const float* out_nb  = (const float*)d_in[9];
  const float* ff_ng   = (const float*)d_in[10];
  const float* ff_nb   = (const float*)d_in[11];
  const float* w1      = (const float*)d_in[12];
  const float* b1      = (const float*)d_in[13];
  const float* w2      = (const float*)d_in[14];
  const float* b2      = (const float*)d_in[15];
  const float* fin_g   = (const float*)d_in[16];
  const float* fin_b   = (const float*)d_in[17];
  const float* w_logit = (const float*)d_in[18];
  const float* b_logit = (const float*)d_in[19];
  float* out = (float*)d_out;

  char* ws = (char*)d_ws;
  size_t off = 0;
  auto alloc = [&](size_t bytes) -> void* {
    void* p = ws + off;
    off = (off + bytes + 255) & ~(size_t)255;
    return p;
  };
  unsigned short* wqkvT = (unsigned short*)alloc(4ull * 3072 * 1024 * 2);
  unsigned short* woT   = (unsigned short*)alloc(4ull * 1024 * 1024 * 2);
  unsigned short* w1T   = (unsigned short*)alloc(4ull * 4096 * 1024 * 2);
  unsigned short* w2T   = (unsigned short*)alloc(4ull * 1024 * 4096 * 2);
  unsigned short* wlogT = (unsigned short*)alloc((size_t)NV * 1024 * 2);
  float*          h     = (float*)alloc((size_t)SEQ * DM * 4);
  unsigned short* ybf   = (unsigned short*)alloc((size_t)SEQ * DM * 2);
  unsigned short* qkvbf = (unsigned short*)alloc((size_t)SEQ * 3 * DM * 2);
  unsigned short* vTb   = (unsigned short*)alloc((size_t)DM * SEQ * 2);
  unsigned short* obf   = (unsigned short*)alloc((size_t)SEQ * DM * 2);
  float*          tmpf  = (float*)alloc((size_t)SEQ * DM * 4);
  unsigned short* ffbf  = (unsigned short*)alloc((size_t)SEQ * FFD * 2);
  float*          slabs = (float*)alloc(4ull * SEQ * DM * 4);
  (void)ws_size; (void)in_sizes; (void)n_in; (void)out_size; (void)tmpf;

  const dim3 B(256);
  const dim3 G2(512);

  k_transpose_bf16<<<dim3(16, 48, 4), B, 0, stream>>>(wqkv, wqkvT, 1024, 3072, (size_t)1024 * 3072);
  k_transpose_bf16<<<dim3(16, 16, 4), B, 0, stream>>>(wo, woT, 1024, 1024, (size_t)1024 * 1024);
  k_transpose_bf16<<<dim3(16, 64, 4), B, 0, stream>>>(w1, w1T, 1024, 4096, (size_t)1024 * 4096);
  k_transpose_bf16<<<dim3(64, 16, 4), B, 0, stream>>>(w2, w2T, 4096, 1024, (size_t)4096 * 1024);
  k_transpose_bf16<<<dim3(16, 500, 1), B, 0, stream>>>(w_logit, wlogT, 1024, NV, 0);

  k_embed<<<SEQ, B, 0, stream>>>(x, tok_emb, pos_emb, h);

  for (int l = 0; l < 4; ++l) {
    k_ln_bf16<<<SEQ, B, 0, stream>>>(h, attn_ng + l * DM, attn_nb + l * DM, ybf);
    k_gemm2<0><<<dim3(192), G2, 0, stream>>>(
        ybf, wqkvT + (size_t)l * 3072 * 1024, nullptr, qkvbf, nullptr, 3072, 1024, 1024, 16);
    k_vT<<<dim3(SEQ / 32, DM / 32), B, 0, stream>>>(qkvbf, vTb);
    k_rela_attn<<<dim3(16, NH), B, 0, stream>>>(qkvbf, vTb, obf);
    // wo: split-K x4 (64 -> 256 blocks, full fill), reduce fused into LN kernel
    k_gemm2<4><<<dim3(64, 4), G2, 0, stream>>>(
        obf, woT + (size_t)l * 1024 * 1024, slabs, nullptr, nullptr, 1024, 1024, 256, 16);
    k_addslab_ln_ln<<<SEQ, B, 0, stream>>>(h, slabs, bo + l * DM,
                                           out_ng + l * DM, out_nb + l * DM,
                                           ff_ng + l * DM, ff_nb + l * DM, ybf);
    k_gemm2<2><<<dim3(256), G2, 0, stream>>>(
        ybf, w1T + (size_t)l * 4096 * 1024, nullptr, ffbf, b1 + l * FFD, 4096, 1024, 1024, 16);
    k_gemm2<4><<<dim3(64, 4), G2, 0, stream>>>(
        ffbf, w2T + (size_t)l * 1024 * 4096, slabs, nullptr, nullptr, 1024, 4096, 1024, 16);
    k_red_add<<<SEQ, B, 0, stream>>>(h, slabs, b2 + l * DM);
  }

  k_ln_bf16<<<SEQ, B, 0, stream>>>(h, fin_g, fin_b, ybf);
  k_gemm3<1><<<dim3(1000), G2, 0, stream>>>(ybf, wlogT, out, nullptr, b_logit, NV, 1024, 8);
}